// Round 6
// baseline (119.405 us; speedup 1.0000x reference)
//
#include <hip/hip_runtime.h>
#include <math.h>

// Problem constants
#define B_SZ   16
#define L_SZ   4096
#define NWIN   4092      // (4096-5)/1+1
#define U3     243       // 3^5
#define UPAD   256

// ws layout (float offsets)
#define COS_OFF 0
#define SIN_OFF 131072                    // 16*2*4096
#define Y_OFF   262144
#define M_OFF   (Y_OFF + 1048576)         // 1310720
#define CT_OFF  (M_OFF + 1048576)         // 2359296
#define APK_OFF (CT_OFF + 65536)          // 2424832  (C packed bf16 hi/lo = 16384 uint4)
#define EXTRA_OFF (APK_OFF + 65536)       // 2490368  (mgemm K-split partials)

typedef __attribute__((ext_vector_type(8))) __bf16 bf16x8;
typedef __attribute__((ext_vector_type(4))) float f32x4;

__device__ __forceinline__ float sel3(int t, float c, float s) {
    return t == 0 ? 1.0f : (t == 1 ? c : s);
}

// ---------------- trig tables ----------------
__global__ __launch_bounds__(256) void trig_ker(const float* __restrict__ x,
                                                float* __restrict__ cosT,
                                                float* __restrict__ sinT) {
    int idx = blockIdx.x * 256 + threadIdx.x;   // < 131072
    float v = x[idx];
    cosT[idx] = cosf(v);
    sinT[idx] = sinf(v);
}

// ---------------- Y = (G ⊗ I_512) E ----------------
__global__ __launch_bounds__(256) void y_ker(const float* __restrict__ E,
                                             const float* __restrict__ theta,
                                             float* __restrict__ Y) {
    int idx = blockIdx.x * 256 + threadIdx.x;   // < 524288
    float th = theta[0];
    float st, ct;
    __sincosf(th, &st, &ct);
    int r = idx >> 10, k = idx & 1023;
    float e0 = E[r * 1024 + k];
    float e1 = E[(512 + r) * 1024 + k];
    Y[r * 1024 + k]         =  ct * e0 - st * e1;
    Y[(512 + r) * 1024 + k] = -st * e0 - ct * e1;
}

// ---------------- M = E^T Y, K-split S into separate partials (no atomics) ----------------
__global__ __launch_bounds__(256, 2) void mgemm_ker(const float* __restrict__ E,
                                                    const float* __restrict__ Y,
                                                    float* __restrict__ M,
                                                    float* __restrict__ Mp_extra) {
    __shared__ float Es[16][64];
    __shared__ float Ys[16][64];
    int bj = blockIdx.x, bk = blockIdx.y, ks = blockIdx.z;
    int tid = threadIdx.x;
    int tx = tid & 15, ty = tid >> 4;
    int lr = tid >> 4, lc = (tid & 15) * 4;
    float acc[4][4];
    #pragma unroll
    for (int i = 0; i < 4; ++i)
        #pragma unroll
        for (int j = 0; j < 4; ++j) acc[i][j] = 0.f;

    int kchunk = 1024 / gridDim.z;
    int k0 = ks * kchunk;
    for (int d0 = k0; d0 < k0 + kchunk; d0 += 16) {
        float4 e = *(const float4*)&E[(d0 + lr) * 1024 + bj * 64 + lc];
        float4 y = *(const float4*)&Y[(d0 + lr) * 1024 + bk * 64 + lc];
        __syncthreads();
        *(float4*)&Es[lr][lc] = e;
        *(float4*)&Ys[lr][lc] = y;
        __syncthreads();
        #pragma unroll
        for (int dd = 0; dd < 16; ++dd) {
            float4 a = *(const float4*)&Es[dd][ty * 4];
            float4 bv = *(const float4*)&Ys[dd][tx * 4];
            acc[0][0] += a.x * bv.x; acc[0][1] += a.x * bv.y; acc[0][2] += a.x * bv.z; acc[0][3] += a.x * bv.w;
            acc[1][0] += a.y * bv.x; acc[1][1] += a.y * bv.y; acc[1][2] += a.y * bv.z; acc[1][3] += a.y * bv.w;
            acc[2][0] += a.z * bv.x; acc[2][1] += a.z * bv.y; acc[2][2] += a.z * bv.z; acc[2][3] += a.z * bv.w;
            acc[3][0] += a.w * bv.x; acc[3][1] += a.w * bv.y; acc[3][2] += a.w * bv.z; acc[3][3] += a.w * bv.w;
        }
    }
    float* dst = (ks == 0) ? M : (Mp_extra + (ks - 1) * 1048576);
    #pragma unroll
    for (int i = 0; i < 4; ++i) {
        float4 r = make_float4(acc[i][0], acc[i][1], acc[i][2], acc[i][3]);
        *(float4*)&dst[(bj * 64 + ty * 4 + i) * 1024 + bk * 64 + tx * 4] = r;
    }
}

// ---------------- C via WHT of generalized diagonals (sums S partials inline) ----------------
__global__ __launch_bounds__(256) void cwht_ker(const float* __restrict__ M,
                                                const float* __restrict__ Mp_extra,
                                                int S,
                                                float* __restrict__ CT) {
    __shared__ float D[1024];
    int mx = blockIdx.x;
    int tid = threadIdx.x;
    #pragma unroll
    for (int k = 0; k < 4; ++k) {
        int j = tid + k * 256;
        int off = j * 1024 + (j ^ mx);
        float v = M[off];
        for (int s = 1; s < S; ++s) v += Mp_extra[(s - 1) * 1048576 + off];
        D[j] = v;
    }
    __syncthreads();
    for (int s = 0; s < 10; ++s) {
        #pragma unroll
        for (int k = 0; k < 2; ++k) {
            int p = tid + k * 256;
            int i = ((p >> s) << (s + 1)) | (p & ((1 << s) - 1));
            int j2 = i | (1 << s);
            float lo = D[i], hi = D[j2];
            D[i] = lo + hi;
            D[j2] = lo - hi;
        }
        __syncthreads();
    }
    for (int mz = tid; mz < 1024; mz += 256) {
        if (mz & mx) continue;
        int u = 0, v = 0;
        #pragma unroll
        for (int i = 0; i < 5; ++i) {
            int bit = 9 - i;
            int t = ((mx >> bit) & 1) ? 2 : (((mz >> bit) & 1) ? 1 : 0);
            u = u * 3 + t;
        }
        #pragma unroll
        for (int i = 5; i < 10; ++i) {
            int bit = 9 - i;
            int t = ((mx >> bit) & 1) ? 2 : (((mz >> bit) & 1) ? 1 : 0);
            v = v * 3 + t;
        }
        CT[v * UPAD + u] = D[mz] * (1.0f / 1024.0f);
    }
    if (mx == 0) {
        for (int e = tid; e < U3 * (UPAD - U3); e += 256) {
            int v = e / (UPAD - U3), q = e % (UPAD - U3);
            CT[v * UPAD + U3 + q] = 0.0f;
        }
        for (int e = tid; e < (256 - U3) * UPAD; e += 256) {
            CT[U3 * UPAD + e] = 0.0f;
        }
    }
}

// ---------------- pack C into MFMA A-fragment order, bf16 hi/lo ----------------
__global__ __launch_bounds__(256) void apack_ker(const float* __restrict__ CT,
                                                 uint4* __restrict__ Apk) {
    int idx = blockIdx.x * 256 + threadIdx.x;    // < 8192
    int l = idx & 63;
    int rest = idx >> 6;
    int ks = rest & 7, ut = rest >> 3;
    int u = ut * 16 + (l & 15);
    int vb = ks * 32 + (l >> 4) * 8;
    unsigned hw[4], lw[4];
    #pragma unroll
    for (int j = 0; j < 8; ++j) {
        float x = CT[(vb + j) * UPAD + u];
        unsigned ux = __float_as_uint(x);
        unsigned hh = ux >> 16;                      // truncation split: lo absorbs the error
        float hf = __uint_as_float(hh << 16);
        float lf = x - hf;
        unsigned ll = __float_as_uint(lf) >> 16;
        if (j & 1) { hw[j >> 1] |= hh << 16; lw[j >> 1] |= ll << 16; }
        else       { hw[j >> 1] = hh;        lw[j >> 1] = ll; }
    }
    Apk[idx]        = make_uint4(hw[0], hw[1], hw[2], hw[3]);
    Apk[8192 + idx] = make_uint4(lw[0], lw[1], lw[2], lw[3]);
}

// ---------------- main: 64 windows/block, MFMA 16x16x32 bf16 3-term split ----------------
// Register-budget 128 (lb 256,4): b-frags per-wt, trig reloaded per-half,
// F0 epilogue fully in registers (global trig loads) — 4 barriers total.
__global__ __launch_bounds__(256, 4) void main_ker(const float* __restrict__ cosT,
                                                   const float* __restrict__ sinT,
                                                   const uint4* __restrict__ Apk,
                                                   float* __restrict__ out) {
    __shared__ __align__(16) unsigned short F1h[16 * 65 * 8];   // 16640 B
    __shared__ __align__(16) unsigned short F1l[16 * 65 * 8];   // 16640 B
    __shared__ float red[16][16];                               // 1024 B

    int tid = threadIdx.x;
    int w0 = blockIdx.x * 64;
    int b  = blockIdx.y;
    int lane = tid & 63;
    int wave = tid >> 6;
    int wb = tid & 63;

    const float* cos1 = cosT + b * 8192 + 4096;
    const float* sin1 = sinT + b * 8192 + 4096;

    f32x4 acc[4][4];
    #pragma unroll
    for (int ut = 0; ut < 4; ++ut)
        #pragma unroll
        for (int wt = 0; wt < 4; ++wt)
            acc[ut][wt] = (f32x4){0.f, 0.f, 0.f, 0.f};

    const uint4* Ahi = Apk;
    const uint4* Alo = Apk + 8192;

    #pragma unroll 1
    for (int h = 0; h < 2; ++h) {
        if (h) __syncthreads();                      // protect F1 from previous MFMA reads
        // ---- build F1 half h (trig loaded fresh per half, dead across MFMA) ----
        {
            float c1r[5], s1r[5];
            #pragma unroll
            for (int k = 0; k < 5; ++k) {
                int pos = w0 + wb + k;
                bool ok = pos < L_SZ;
                c1r[k] = ok ? cos1[pos] : 0.f;
                s1r[k] = ok ? sin1[pos] : 0.f;
            }
            int gv = h * 128 + wave * 32;               // wave-uniform v base
            int t0 = gv / 81; int rr = gv - t0 * 81;
            int t1 = rr / 27; rr -= t1 * 27;
            int t2 = rr / 9;  rr -= t2 * 9;
            int t3 = rr / 3;  int t4 = rr - t3 * 3;
            float g0 = sel3(t0, c1r[0], s1r[0]);
            float g1 = sel3(t1, c1r[1], s1r[1]);
            float g2 = sel3(t2, c1r[2], s1r[2]);
            float g3 = sel3(t3, c1r[3], s1r[3]);
            float p01 = g0 * g1, p012 = p01 * g2, p0123 = p012 * g3;
            #pragma unroll
            for (int p8 = 0; p8 < 4; ++p8) {
                unsigned hw[4], lw[4];
                #pragma unroll
                for (int i = 0; i < 8; ++i) {
                    int gvv = gv + p8 * 8 + i;
                    float val = p0123 * sel3(t4, c1r[4], s1r[4]);
                    if (gvv >= U3) val = 0.f;
                    unsigned ux = __float_as_uint(val);
                    unsigned hh = ux >> 16;
                    float hf = __uint_as_float(hh << 16);
                    float lf = val - hf;
                    unsigned ll = __float_as_uint(lf) >> 16;
                    if (i & 1) { hw[i >> 1] |= hh << 16; lw[i >> 1] |= ll << 16; }
                    else       { hw[i >> 1] = hh;        lw[i >> 1] = ll; }
                    if (++t4 == 3) { t4 = 0;
                        if (++t3 == 3) { t3 = 0;
                            if (++t2 == 3) { t2 = 0;
                                if (++t1 == 3) { t1 = 0; ++t0; g0 = sel3(t0, c1r[0], s1r[0]); }
                                g1 = sel3(t1, c1r[1], s1r[1]); p01 = g0 * g1;
                            }
                            g2 = sel3(t2, c1r[2], s1r[2]); p012 = p01 * g2;
                        }
                        g3 = sel3(t3, c1r[3], s1r[3]); p0123 = p012 * g3;
                    }
                }
                int vp = wave * 4 + p8;
                *(uint4*)&F1h[(vp * 65 + wb) * 8] = make_uint4(hw[0], hw[1], hw[2], hw[3]);
                *(uint4*)&F1l[(vp * 65 + wb) * 8] = make_uint4(lw[0], lw[1], lw[2], lw[3]);
            }
        }
        __syncthreads();

        // ---- MFMA over this half's 4 K-steps ----
        #pragma unroll
        for (int kl = 0; kl < 4; ++kl) {
            int ks = h * 4 + kl;
            uint4 a_h[4], a_l[4];
            #pragma unroll
            for (int ut = 0; ut < 4; ++ut) {
                int idx = ((wave * 4 + ut) * 8 + ks) * 64 + lane;
                a_h[ut] = Ahi[idx];
                a_l[ut] = Alo[idx];
            }
            int vp = kl * 4 + (lane >> 4);
            #pragma unroll
            for (int wt = 0; wt < 4; ++wt) {
                int off = (vp * 65 + wt * 16 + (lane & 15)) * 8;
                uint4 b_h = *(const uint4*)&F1h[off];
                uint4 b_l = *(const uint4*)&F1l[off];
                bf16x8 bh = __builtin_bit_cast(bf16x8, b_h);
                bf16x8 bl = __builtin_bit_cast(bf16x8, b_l);
                #pragma unroll
                for (int ut = 0; ut < 4; ++ut) {
                    bf16x8 ah = __builtin_bit_cast(bf16x8, a_h[ut]);
                    bf16x8 al = __builtin_bit_cast(bf16x8, a_l[ut]);
                    acc[ut][wt] = __builtin_amdgcn_mfma_f32_16x16x32_bf16(ah, bh, acc[ut][wt], 0, 0, 0);
                    acc[ut][wt] = __builtin_amdgcn_mfma_f32_16x16x32_bf16(ah, bl, acc[ut][wt], 0, 0, 0);
                    acc[ut][wt] = __builtin_amdgcn_mfma_f32_16x16x32_bf16(al, bh, acc[ut][wt], 0, 0, 0);
                }
            }
        }
    }

    // ---- epilogue: z[w] = sum_u F0[u,w]*G[u,w] — F0 entirely in registers.
    //      acc[ut][wt][r] = G[u,w], u = wave*64+ut*16+(lane>>4)*4+r, w = wt*16+(lane&15).
    //      u>=243 rows of acc are 0 (CT pad), so garbage digits there are harmless. ----
    const float* cos0 = cosT + b * 8192;
    const float* sin0 = sinT + b * 8192;
    int c = lane & 15;
    float c0r[4][5], s0r[4][5];
    #pragma unroll
    for (int wt = 0; wt < 4; ++wt)
        #pragma unroll
        for (int k = 0; k < 5; ++k) {
            int pos = w0 + wt * 16 + c + k;
            bool ok = pos < L_SZ;
            c0r[wt][k] = ok ? cos0[pos] : 0.f;
            s0r[wt][k] = ok ? sin0[pos] : 0.f;
        }
    float zcol[4] = {0.f, 0.f, 0.f, 0.f};
    #pragma unroll
    for (int ut = 0; ut < 4; ++ut) {
        int ubase = wave * 64 + ut * 16 + ((lane >> 4) << 2);
        #pragma unroll
        for (int r = 0; r < 4; ++r) {
            int u = ubase + r;
            int t0 = u / 81; int rr = u - t0 * 81;
            int t1 = rr / 27; rr -= t1 * 27;
            int t2 = rr / 9;  rr -= t2 * 9;
            int t3 = rr / 3;  int t4 = rr - t3 * 3;
            #pragma unroll
            for (int wt = 0; wt < 4; ++wt) {
                float f = sel3(t0, c0r[wt][0], s0r[wt][0]) * sel3(t1, c0r[wt][1], s0r[wt][1])
                        * sel3(t2, c0r[wt][2], s0r[wt][2]) * sel3(t3, c0r[wt][3], s0r[wt][3])
                        * sel3(t4, c0r[wt][4], s0r[wt][4]);
                zcol[wt] += f * acc[ut][wt][r];
            }
        }
    }

    // ---- reduce over u-groups: in-wave (lane>>4), then across 4 waves via LDS ----
    #pragma unroll
    for (int wt = 0; wt < 4; ++wt) {
        float v = zcol[wt];
        v += __shfl_xor(v, 16, 64);
        v += __shfl_xor(v, 32, 64);
        if ((lane >> 4) == 0) red[wave * 4 + wt][lane] = v;
    }
    __syncthreads();
    if (tid < 64) {
        int wt = tid >> 4, cc = tid & 15;
        float z = red[0 * 4 + wt][cc] + red[1 * 4 + wt][cc]
                + red[2 * 4 + wt][cc] + red[3 * 4 + wt][cc];
        int w = wt * 16 + cc;
        if (w0 + w < NWIN) out[b * NWIN + w0 + w] = z;
    }
}

extern "C" void kernel_launch(void* const* d_in, const int* in_sizes, int n_in,
                              void* d_out, int out_size, void* d_ws, size_t ws_size,
                              hipStream_t stream) {
    const float* x     = (const float*)d_in[0];
    const float* E     = (const float*)d_in[1];
    const float* theta = (const float*)d_in[2];
    float* out = (float*)d_out;
    float* ws = (float*)d_ws;

    float* cosT = ws + COS_OFF;
    float* sinT = ws + SIN_OFF;
    float* Y    = ws + Y_OFF;
    float* M    = ws + M_OFF;
    float* CT   = ws + CT_OFF;
    uint4* Apk  = (uint4*)(ws + APK_OFF);
    float* Mx   = ws + EXTRA_OFF;

    size_t need4 = (size_t)(EXTRA_OFF + 3 * 1048576) * 4;
    size_t need2 = (size_t)(EXTRA_OFF + 1 * 1048576) * 4;
    int S = (ws_size >= need4) ? 4 : ((ws_size >= need2) ? 2 : 1);

    trig_ker<<<512, 256, 0, stream>>>(x, cosT, sinT);
    y_ker<<<2048, 256, 0, stream>>>(E, theta, Y);
    mgemm_ker<<<dim3(16, 16, S), 256, 0, stream>>>(E, Y, M, Mx);
    cwht_ker<<<1024, 256, 0, stream>>>(M, Mx, S, CT);
    apack_ker<<<32, 256, 0, stream>>>(CT, Apk);
    main_ker<<<dim3(64, 16), 256, 0, stream>>>(cosT, sinT, Apk, out);
}

// Round 7
// 100.847 us; speedup vs baseline: 1.1840x; 1.1840x over previous
//
#include <hip/hip_runtime.h>
#include <math.h>

// Problem constants
#define B_SZ   16
#define L_SZ   4096
#define NWIN   4092      // (4096-5)/1+1
#define U3     243       // 3^5
#define UPAD   256

// ws layout (float offsets)
#define COS_OFF 0
#define SIN_OFF 131072                    // 16*2*4096
#define Y_OFF   262144
#define M_OFF   (Y_OFF + 1048576)         // 1310720
#define CT_OFF  (M_OFF + 1048576)         // 2359296
#define APK_OFF (CT_OFF + 65536)          // 2424832  (C packed bf16 hi/lo = 16384 uint4)
#define EXTRA_OFF (APK_OFF + 65536)       // 2490368  (mgemm K-split partials)

typedef __attribute__((ext_vector_type(8))) __bf16 bf16x8;
typedef __attribute__((ext_vector_type(4))) float f32x4;

__device__ __forceinline__ float sel3(int t, float c, float s) {
    return t == 0 ? 1.0f : (t == 1 ? c : s);
}

// ---------------- trig tables ----------------
__global__ __launch_bounds__(256) void trig_ker(const float* __restrict__ x,
                                                float* __restrict__ cosT,
                                                float* __restrict__ sinT) {
    int idx = blockIdx.x * 256 + threadIdx.x;   // < 131072
    float v = x[idx];
    cosT[idx] = cosf(v);
    sinT[idx] = sinf(v);
}

// ---------------- Y = (G ⊗ I_512) E ----------------
__global__ __launch_bounds__(256) void y_ker(const float* __restrict__ E,
                                             const float* __restrict__ theta,
                                             float* __restrict__ Y) {
    int idx = blockIdx.x * 256 + threadIdx.x;   // < 524288
    float th = theta[0];
    float st, ct;
    __sincosf(th, &st, &ct);
    int r = idx >> 10, k = idx & 1023;
    float e0 = E[r * 1024 + k];
    float e1 = E[(512 + r) * 1024 + k];
    Y[r * 1024 + k]         =  ct * e0 - st * e1;
    Y[(512 + r) * 1024 + k] = -st * e0 - ct * e1;
}

// ---------------- M = E^T Y (SYMMETRIC: upper-triangle blocks only), K-split S ----------------
__global__ __launch_bounds__(256, 2) void mgemm_ker(const float* __restrict__ E,
                                                    const float* __restrict__ Y,
                                                    float* __restrict__ M,
                                                    float* __restrict__ Mp_extra) {
    __shared__ float Es[16][64];
    __shared__ float Ys[16][64];
    // map linear triangle index -> (bj, bk), bj <= bk
    int t = blockIdx.x;
    int bj = 0;
    while (t >= 16 - bj) { t -= 16 - bj; ++bj; }
    int bk = bj + t;
    int ks = blockIdx.z;
    int tid = threadIdx.x;
    int tx = tid & 15, ty = tid >> 4;
    int lr = tid >> 4, lc = (tid & 15) * 4;
    float acc[4][4];
    #pragma unroll
    for (int i = 0; i < 4; ++i)
        #pragma unroll
        for (int j = 0; j < 4; ++j) acc[i][j] = 0.f;

    int kchunk = 1024 / gridDim.z;
    int k0 = ks * kchunk;
    for (int d0 = k0; d0 < k0 + kchunk; d0 += 16) {
        float4 e = *(const float4*)&E[(d0 + lr) * 1024 + bj * 64 + lc];
        float4 y = *(const float4*)&Y[(d0 + lr) * 1024 + bk * 64 + lc];
        __syncthreads();
        *(float4*)&Es[lr][lc] = e;
        *(float4*)&Ys[lr][lc] = y;
        __syncthreads();
        #pragma unroll
        for (int dd = 0; dd < 16; ++dd) {
            float4 a = *(const float4*)&Es[dd][ty * 4];
            float4 bv = *(const float4*)&Ys[dd][tx * 4];
            acc[0][0] += a.x * bv.x; acc[0][1] += a.x * bv.y; acc[0][2] += a.x * bv.z; acc[0][3] += a.x * bv.w;
            acc[1][0] += a.y * bv.x; acc[1][1] += a.y * bv.y; acc[1][2] += a.y * bv.z; acc[1][3] += a.y * bv.w;
            acc[2][0] += a.z * bv.x; acc[2][1] += a.z * bv.y; acc[2][2] += a.z * bv.z; acc[2][3] += a.z * bv.w;
            acc[3][0] += a.w * bv.x; acc[3][1] += a.w * bv.y; acc[3][2] += a.w * bv.z; acc[3][3] += a.w * bv.w;
        }
    }
    float* dst = (ks == 0) ? M : (Mp_extra + (ks - 1) * 1048576);
    #pragma unroll
    for (int i = 0; i < 4; ++i) {
        float4 r = make_float4(acc[i][0], acc[i][1], acc[i][2], acc[i][3]);
        *(float4*)&dst[(bj * 64 + ty * 4 + i) * 1024 + bk * 64 + tx * 4] = r;
    }
}

// ---------------- C via WHT of generalized diagonals (symmetric-M gather, sums S partials) ----------------
__global__ __launch_bounds__(256) void cwht_ker(const float* __restrict__ M,
                                                const float* __restrict__ Mp_extra,
                                                int S,
                                                float* __restrict__ CT) {
    __shared__ float D[1024];
    int mx = blockIdx.x;
    int tid = threadIdx.x;
    #pragma unroll
    for (int k = 0; k < 4; ++k) {
        int j = tid + k * 256;
        int p = j ^ mx;
        int rmin = p < j ? p : j;
        int cmax = p < j ? j : p;
        int off = rmin * 1024 + cmax;          // M symmetric: only upper triangle stored
        float v = M[off];
        for (int s = 1; s < S; ++s) v += Mp_extra[(s - 1) * 1048576 + off];
        D[j] = v;
    }
    __syncthreads();
    for (int s = 0; s < 10; ++s) {
        #pragma unroll
        for (int k = 0; k < 2; ++k) {
            int p = tid + k * 256;
            int i = ((p >> s) << (s + 1)) | (p & ((1 << s) - 1));
            int j2 = i | (1 << s);
            float lo = D[i], hi = D[j2];
            D[i] = lo + hi;
            D[j2] = lo - hi;
        }
        __syncthreads();
    }
    for (int mz = tid; mz < 1024; mz += 256) {
        if (mz & mx) continue;
        int u = 0, v = 0;
        #pragma unroll
        for (int i = 0; i < 5; ++i) {
            int bit = 9 - i;
            int t = ((mx >> bit) & 1) ? 2 : (((mz >> bit) & 1) ? 1 : 0);
            u = u * 3 + t;
        }
        #pragma unroll
        for (int i = 5; i < 10; ++i) {
            int bit = 9 - i;
            int t = ((mx >> bit) & 1) ? 2 : (((mz >> bit) & 1) ? 1 : 0);
            v = v * 3 + t;
        }
        CT[v * UPAD + u] = D[mz] * (1.0f / 1024.0f);
    }
    if (mx == 0) {
        for (int e = tid; e < U3 * (UPAD - U3); e += 256) {
            int v = e / (UPAD - U3), q = e % (UPAD - U3);
            CT[v * UPAD + U3 + q] = 0.0f;
        }
        for (int e = tid; e < (256 - U3) * UPAD; e += 256) {
            CT[U3 * UPAD + e] = 0.0f;
        }
    }
}

// ---------------- pack C into MFMA A-fragment order, bf16 hi/lo ----------------
__global__ __launch_bounds__(256) void apack_ker(const float* __restrict__ CT,
                                                 uint4* __restrict__ Apk) {
    int idx = blockIdx.x * 256 + threadIdx.x;    // < 8192
    int l = idx & 63;
    int rest = idx >> 6;
    int ks = rest & 7, ut = rest >> 3;
    int u = ut * 16 + (l & 15);
    int vb = ks * 32 + (l >> 4) * 8;
    unsigned hw[4], lw[4];
    #pragma unroll
    for (int j = 0; j < 8; ++j) {
        float x = CT[(vb + j) * UPAD + u];
        unsigned ux = __float_as_uint(x);
        unsigned hh = ux >> 16;                      // truncation split: lo absorbs the error
        float hf = __uint_as_float(hh << 16);
        float lf = x - hf;
        unsigned ll = __float_as_uint(lf) >> 16;
        if (j & 1) { hw[j >> 1] |= hh << 16; lw[j >> 1] |= ll << 16; }
        else       { hw[j >> 1] = hh;        lw[j >> 1] = ll; }
    }
    Apk[idx]        = make_uint4(hw[0], hw[1], hw[2], hw[3]);
    Apk[8192 + idx] = make_uint4(lw[0], lw[1], lw[2], lw[3]);
}

// ---------------- main: 64 windows/block, MFMA 16x16x32 bf16 3-term split ----------------
// Single-phase F1 (all 256 v in LDS), trig staged once into LDS trg,
// register-F0 epilogue sourced from LDS trg (no global scatter). 4 barriers total.
__global__ __launch_bounds__(256, 2) void main_ker(const float* __restrict__ cosT,
                                                   const float* __restrict__ sinT,
                                                   const uint4* __restrict__ Apk,
                                                   float* __restrict__ out) {
    __shared__ float trg[4][68];                                // c1,s1,c0,s0
    __shared__ __align__(16) unsigned short F1h[32 * 65 * 8];   // 33280 B
    __shared__ __align__(16) unsigned short F1l[32 * 65 * 8];   // 33280 B
    __shared__ float red[16][16];                               // 1024 B

    int tid = threadIdx.x;
    int w0 = blockIdx.x * 64;
    int b  = blockIdx.y;
    int lane = tid & 63;
    int wave = tid >> 6;
    int wb = tid & 63;

    // stage trig rows once (coalesced, 68 floats x 4 rows)
    for (int p = tid; p < 68; p += 256) {
        int pos = w0 + p;
        bool ok = pos < L_SZ;
        trg[0][p] = ok ? cosT[b * 8192 + 4096 + pos] : 0.f;
        trg[1][p] = ok ? sinT[b * 8192 + 4096 + pos] : 0.f;
        trg[2][p] = ok ? cosT[b * 8192 + pos] : 0.f;
        trg[3][p] = ok ? sinT[b * 8192 + pos] : 0.f;
    }

    f32x4 acc[4][4];
    #pragma unroll
    for (int ut = 0; ut < 4; ++ut)
        #pragma unroll
        for (int wt = 0; wt < 4; ++wt)
            acc[ut][wt] = (f32x4){0.f, 0.f, 0.f, 0.f};

    __syncthreads();

    // ---- build F1 for ALL 256 v (wave w owns vp rows w*8..w*8+8, column wb) ----
    {
        float c1r[5], s1r[5];
        #pragma unroll
        for (int k = 0; k < 5; ++k) { c1r[k] = trg[0][wb + k]; s1r[k] = trg[1][wb + k]; }
        int gv = wave * 64;                          // wave-uniform v base
        int t0 = gv / 81; int rr = gv - t0 * 81;
        int t1 = rr / 27; rr -= t1 * 27;
        int t2 = rr / 9;  rr -= t2 * 9;
        int t3 = rr / 3;  int t4 = rr - t3 * 3;
        float g0 = sel3(t0, c1r[0], s1r[0]);
        float g1 = sel3(t1, c1r[1], s1r[1]);
        float g2 = sel3(t2, c1r[2], s1r[2]);
        float g3 = sel3(t3, c1r[3], s1r[3]);
        float p01 = g0 * g1, p012 = p01 * g2, p0123 = p012 * g3;
        #pragma unroll
        for (int p8 = 0; p8 < 8; ++p8) {
            unsigned hw[4], lw[4];
            #pragma unroll
            for (int i = 0; i < 8; ++i) {
                int gvv = gv + p8 * 8 + i;
                float val = p0123 * sel3(t4, c1r[4], s1r[4]);
                if (gvv >= U3) val = 0.f;
                unsigned ux = __float_as_uint(val);
                unsigned hh = ux >> 16;
                float hf = __uint_as_float(hh << 16);
                float lf = val - hf;
                unsigned ll = __float_as_uint(lf) >> 16;
                if (i & 1) { hw[i >> 1] |= hh << 16; lw[i >> 1] |= ll << 16; }
                else       { hw[i >> 1] = hh;        lw[i >> 1] = ll; }
                if (++t4 == 3) { t4 = 0;
                    if (++t3 == 3) { t3 = 0;
                        if (++t2 == 3) { t2 = 0;
                            if (++t1 == 3) { t1 = 0; ++t0; g0 = sel3(t0, c1r[0], s1r[0]); }
                            g1 = sel3(t1, c1r[1], s1r[1]); p01 = g0 * g1;
                        }
                        g2 = sel3(t2, c1r[2], s1r[2]); p012 = p01 * g2;
                    }
                    g3 = sel3(t3, c1r[3], s1r[3]); p0123 = p012 * g3;
                }
            }
            int vp = wave * 8 + p8;
            *(uint4*)&F1h[(vp * 65 + wb) * 8] = make_uint4(hw[0], hw[1], hw[2], hw[3]);
            *(uint4*)&F1l[(vp * 65 + wb) * 8] = make_uint4(lw[0], lw[1], lw[2], lw[3]);
        }
    }
    __syncthreads();

    // ---- MFMA: all 8 K-steps, no intervening barriers (max MLP/ILP) ----
    const uint4* Ahi = Apk;
    const uint4* Alo = Apk + 8192;
    #pragma unroll 4
    for (int ks = 0; ks < 8; ++ks) {
        uint4 a_h[4], a_l[4];
        #pragma unroll
        for (int ut = 0; ut < 4; ++ut) {
            int idx = ((wave * 4 + ut) * 8 + ks) * 64 + lane;
            a_h[ut] = Ahi[idx];
            a_l[ut] = Alo[idx];
        }
        int vp = ks * 4 + (lane >> 4);
        #pragma unroll
        for (int wt = 0; wt < 4; ++wt) {
            int off = (vp * 65 + wt * 16 + (lane & 15)) * 8;
            uint4 b_h = *(const uint4*)&F1h[off];
            uint4 b_l = *(const uint4*)&F1l[off];
            bf16x8 bh = __builtin_bit_cast(bf16x8, b_h);
            bf16x8 bl = __builtin_bit_cast(bf16x8, b_l);
            #pragma unroll
            for (int ut = 0; ut < 4; ++ut) {
                bf16x8 ah = __builtin_bit_cast(bf16x8, a_h[ut]);
                bf16x8 al = __builtin_bit_cast(bf16x8, a_l[ut]);
                acc[ut][wt] = __builtin_amdgcn_mfma_f32_16x16x32_bf16(ah, bh, acc[ut][wt], 0, 0, 0);
                acc[ut][wt] = __builtin_amdgcn_mfma_f32_16x16x32_bf16(ah, bl, acc[ut][wt], 0, 0, 0);
                acc[ut][wt] = __builtin_amdgcn_mfma_f32_16x16x32_bf16(al, bh, acc[ut][wt], 0, 0, 0);
            }
        }
    }

    // ---- epilogue: z[w] = sum_u F0[u,w]*G[u,w], F0 in registers from LDS trg.
    //      acc[ut][wt][r]: u = wave*64+ut*16+(lane>>4)*4+r, w = wt*16+(lane&15).
    //      u>=243 rows of acc are 0 (CT pad) so garbage digits there are harmless. ----
    int c = lane & 15;
    float c0r[4][5], s0r[4][5];
    #pragma unroll
    for (int wt = 0; wt < 4; ++wt)
        #pragma unroll
        for (int k = 0; k < 5; ++k) {
            c0r[wt][k] = trg[2][wt * 16 + c + k];
            s0r[wt][k] = trg[3][wt * 16 + c + k];
        }
    float zcol[4] = {0.f, 0.f, 0.f, 0.f};
    #pragma unroll
    for (int ut = 0; ut < 4; ++ut) {
        int ubase = wave * 64 + ut * 16 + ((lane >> 4) << 2);
        #pragma unroll
        for (int r = 0; r < 4; ++r) {
            int u = ubase + r;
            int t0 = u / 81; int rr = u - t0 * 81;
            int t1 = rr / 27; rr -= t1 * 27;
            int t2 = rr / 9;  rr -= t2 * 9;
            int t3 = rr / 3;  int t4 = rr - t3 * 3;
            #pragma unroll
            for (int wt = 0; wt < 4; ++wt) {
                float f = sel3(t0, c0r[wt][0], s0r[wt][0]) * sel3(t1, c0r[wt][1], s0r[wt][1])
                        * sel3(t2, c0r[wt][2], s0r[wt][2]) * sel3(t3, c0r[wt][3], s0r[wt][3])
                        * sel3(t4, c0r[wt][4], s0r[wt][4]);
                zcol[wt] += f * acc[ut][wt][r];
            }
        }
    }

    // ---- reduce over u-groups: in-wave (lane>>4), then across 4 waves via LDS ----
    #pragma unroll
    for (int wt = 0; wt < 4; ++wt) {
        float v = zcol[wt];
        v += __shfl_xor(v, 16, 64);
        v += __shfl_xor(v, 32, 64);
        if ((lane >> 4) == 0) red[wave * 4 + wt][lane] = v;
    }
    __syncthreads();
    if (tid < 64) {
        int wt = tid >> 4, cc = tid & 15;
        float z = red[0 * 4 + wt][cc] + red[1 * 4 + wt][cc]
                + red[2 * 4 + wt][cc] + red[3 * 4 + wt][cc];
        int w = wt * 16 + cc;
        if (w0 + w < NWIN) out[b * NWIN + w0 + w] = z;
    }
}

extern "C" void kernel_launch(void* const* d_in, const int* in_sizes, int n_in,
                              void* d_out, int out_size, void* d_ws, size_t ws_size,
                              hipStream_t stream) {
    const float* x     = (const float*)d_in[0];
    const float* E     = (const float*)d_in[1];
    const float* theta = (const float*)d_in[2];
    float* out = (float*)d_out;
    float* ws = (float*)d_ws;

    float* cosT = ws + COS_OFF;
    float* sinT = ws + SIN_OFF;
    float* Y    = ws + Y_OFF;
    float* M    = ws + M_OFF;
    float* CT   = ws + CT_OFF;
    uint4* Apk  = (uint4*)(ws + APK_OFF);
    float* Mx   = ws + EXTRA_OFF;

    size_t need4 = (size_t)(EXTRA_OFF + 3 * 1048576) * 4;
    size_t need2 = (size_t)(EXTRA_OFF + 1 * 1048576) * 4;
    int S = (ws_size >= need4) ? 4 : ((ws_size >= need2) ? 2 : 1);

    trig_ker<<<512, 256, 0, stream>>>(x, cosT, sinT);
    y_ker<<<2048, 256, 0, stream>>>(E, theta, Y);
    mgemm_ker<<<dim3(136, 1, S), 256, 0, stream>>>(E, Y, M, Mx);
    cwht_ker<<<1024, 256, 0, stream>>>(M, Mx, S, CT);
    apack_ker<<<32, 256, 0, stream>>>(CT, Apk);
    main_ker<<<dim3(64, 16), 256, 0, stream>>>(cosT, sinT, Apk, out);
}

// Round 8
// 99.829 us; speedup vs baseline: 1.1961x; 1.0102x over previous
//
#include <hip/hip_runtime.h>
#include <math.h>

// Problem constants
#define B_SZ   16
#define L_SZ   4096
#define NWIN   4092      // (4096-5)/1+1
#define U3     243       // 3^5
#define UPAD   256

// ws layout (float offsets)
#define COS_OFF 0
#define SIN_OFF 131072                    // 16*2*4096
#define Y_OFF   262144
#define M_OFF   (Y_OFF + 1048576)         // 1310720
#define CT_OFF  (M_OFF + 1048576)         // 2359296
#define APK_OFF (CT_OFF + 65536)          // 2424832  (C packed bf16 hi/lo = 16384 uint4)
#define EXTRA_OFF (APK_OFF + 65536)       // 2490368  (mgemm K-split partials)

typedef __attribute__((ext_vector_type(8))) __bf16 bf16x8;
typedef __attribute__((ext_vector_type(4))) float f32x4;

__device__ __forceinline__ float sel3(int t, float c, float s) {
    return t == 0 ? 1.0f : (t == 1 ? c : s);
}

// ---------------- trig tables ----------------
__global__ __launch_bounds__(256) void trig_ker(const float* __restrict__ x,
                                                float* __restrict__ cosT,
                                                float* __restrict__ sinT) {
    int idx = blockIdx.x * 256 + threadIdx.x;   // < 131072
    float v = x[idx];
    cosT[idx] = cosf(v);
    sinT[idx] = sinf(v);
}

// ---------------- Y = (G ⊗ I_512) E ----------------
__global__ __launch_bounds__(256) void y_ker(const float* __restrict__ E,
                                             const float* __restrict__ theta,
                                             float* __restrict__ Y) {
    int idx = blockIdx.x * 256 + threadIdx.x;   // < 524288
    float th = theta[0];
    float st, ct;
    __sincosf(th, &st, &ct);
    int r = idx >> 10, k = idx & 1023;
    float e0 = E[r * 1024 + k];
    float e1 = E[(512 + r) * 1024 + k];
    Y[r * 1024 + k]         =  ct * e0 - st * e1;
    Y[(512 + r) * 1024 + k] = -st * e0 - ct * e1;
}

// ---------------- M = E^T Y (symmetric, upper-triangle 64-blocks), TILE-32 layout ----------------
// element (r,c) stored at [((r>>5)*32 + (c>>5))*1024 + (r&31)*32 + (c&31)]
__global__ __launch_bounds__(256, 2) void mgemm_ker(const float* __restrict__ E,
                                                    const float* __restrict__ Y,
                                                    float* __restrict__ M,
                                                    float* __restrict__ Mp_extra) {
    __shared__ float Es[16][64];
    __shared__ float Ys[16][64];
    int t = blockIdx.x;
    int bj = 0;
    while (t >= 16 - bj) { t -= 16 - bj; ++bj; }
    int bk = bj + t;
    int ks = blockIdx.z;
    int tid = threadIdx.x;
    int tx = tid & 15, ty = tid >> 4;
    int lr = tid >> 4, lc = (tid & 15) * 4;
    float acc[4][4];
    #pragma unroll
    for (int i = 0; i < 4; ++i)
        #pragma unroll
        for (int j = 0; j < 4; ++j) acc[i][j] = 0.f;

    int kchunk = 1024 / gridDim.z;
    int k0 = ks * kchunk;
    for (int d0 = k0; d0 < k0 + kchunk; d0 += 16) {
        float4 e = *(const float4*)&E[(d0 + lr) * 1024 + bj * 64 + lc];
        float4 y = *(const float4*)&Y[(d0 + lr) * 1024 + bk * 64 + lc];
        __syncthreads();
        *(float4*)&Es[lr][lc] = e;
        *(float4*)&Ys[lr][lc] = y;
        __syncthreads();
        #pragma unroll
        for (int dd = 0; dd < 16; ++dd) {
            float4 a = *(const float4*)&Es[dd][ty * 4];
            float4 bv = *(const float4*)&Ys[dd][tx * 4];
            acc[0][0] += a.x * bv.x; acc[0][1] += a.x * bv.y; acc[0][2] += a.x * bv.z; acc[0][3] += a.x * bv.w;
            acc[1][0] += a.y * bv.x; acc[1][1] += a.y * bv.y; acc[1][2] += a.y * bv.z; acc[1][3] += a.y * bv.w;
            acc[2][0] += a.z * bv.x; acc[2][1] += a.z * bv.y; acc[2][2] += a.z * bv.z; acc[2][3] += a.z * bv.w;
            acc[3][0] += a.w * bv.x; acc[3][1] += a.w * bv.y; acc[3][2] += a.w * bv.z; acc[3][3] += a.w * bv.w;
        }
    }
    float* dst = (ks == 0) ? M : (Mp_extra + (ks - 1) * 1048576);
    int cb = bk * 64 + tx * 4;
    int kh = cb >> 5, kl = cb & 31;
    #pragma unroll
    for (int i = 0; i < 4; ++i) {
        int r = bj * 64 + ty * 4 + i;
        int jh = r >> 5, jl = r & 31;
        float4 rv = make_float4(acc[i][0], acc[i][1], acc[i][2], acc[i][3]);
        *(float4*)&dst[((jh * 32 + kh) * 32 + jl) * 32 + kl] = rv;
    }
}

// ---------------- C via WHT of generalized diagonals (tiled symmetric gather) ----------------
__global__ __launch_bounds__(256) void cwht_ker(const float* __restrict__ M,
                                                const float* __restrict__ Mp_extra,
                                                int S,
                                                float* __restrict__ CT) {
    __shared__ float D[1024];
    int mx = blockIdx.x;
    int mxh = mx >> 5, mxl = mx & 31;
    int tid = threadIdx.x;
    #pragma unroll
    for (int k = 0; k < 4; ++k) {
        int j = tid + k * 256;
        int jh = j >> 5, jl = j & 31;
        int kh = jh ^ mxh, kl = jl ^ mxl;
        int off;
        if ((jh >> 1) <= (kh >> 1)) off = ((jh * 32 + kh) * 32 + jl) * 32 + kl;
        else                        off = ((kh * 32 + jh) * 32 + kl) * 32 + jl;  // symmetric image
        float v = M[off];
        for (int s = 1; s < S; ++s) v += Mp_extra[(s - 1) * 1048576 + off];
        D[j] = v;
    }
    __syncthreads();
    for (int s = 0; s < 10; ++s) {
        #pragma unroll
        for (int k = 0; k < 2; ++k) {
            int p = tid + k * 256;
            int i = ((p >> s) << (s + 1)) | (p & ((1 << s) - 1));
            int j2 = i | (1 << s);
            float lo = D[i], hi = D[j2];
            D[i] = lo + hi;
            D[j2] = lo - hi;
        }
        __syncthreads();
    }
    for (int mz = tid; mz < 1024; mz += 256) {
        if (mz & mx) continue;
        int u = 0, v = 0;
        #pragma unroll
        for (int i = 0; i < 5; ++i) {
            int bit = 9 - i;
            int t = ((mx >> bit) & 1) ? 2 : (((mz >> bit) & 1) ? 1 : 0);
            u = u * 3 + t;
        }
        #pragma unroll
        for (int i = 5; i < 10; ++i) {
            int bit = 9 - i;
            int t = ((mx >> bit) & 1) ? 2 : (((mz >> bit) & 1) ? 1 : 0);
            v = v * 3 + t;
        }
        CT[v * UPAD + u] = D[mz] * (1.0f / 1024.0f);
    }
    if (mx == 0) {
        for (int e = tid; e < U3 * (UPAD - U3); e += 256) {
            int v = e / (UPAD - U3), q = e % (UPAD - U3);
            CT[v * UPAD + U3 + q] = 0.0f;
        }
        for (int e = tid; e < (256 - U3) * UPAD; e += 256) {
            CT[U3 * UPAD + e] = 0.0f;
        }
    }
}

// ---------------- pack C into MFMA A-fragment order, bf16 hi/lo ----------------
__global__ __launch_bounds__(256) void apack_ker(const float* __restrict__ CT,
                                                 uint4* __restrict__ Apk) {
    int idx = blockIdx.x * 256 + threadIdx.x;    // < 8192
    int l = idx & 63;
    int rest = idx >> 6;
    int ks = rest & 7, ut = rest >> 3;
    int u = ut * 16 + (l & 15);
    int vb = ks * 32 + (l >> 4) * 8;
    unsigned hw[4], lw[4];
    #pragma unroll
    for (int j = 0; j < 8; ++j) {
        float x = CT[(vb + j) * UPAD + u];
        unsigned ux = __float_as_uint(x);
        unsigned hh = ux >> 16;
        float hf = __uint_as_float(hh << 16);
        float lf = x - hf;
        unsigned ll = __float_as_uint(lf) >> 16;
        if (j & 1) { hw[j >> 1] |= hh << 16; lw[j >> 1] |= ll << 16; }
        else       { hw[j >> 1] = hh;        lw[j >> 1] = ll; }
    }
    Apk[idx]        = make_uint4(hw[0], hw[1], hw[2], hw[3]);
    Apk[8192 + idx] = make_uint4(lw[0], lw[1], lw[2], lw[3]);
}

// ---------------- main: 64 windows/block, MFMA 16x16x32 bf16 3-term split ----------------
// Two-phase F1 (35 KB LDS -> 4 blocks/CU), SCALARIZED digit chain (readfirstlane),
// byte_perm hi/lo packing, register-F0 epilogue from LDS trg.
__global__ __launch_bounds__(256, 4) void main_ker(const float* __restrict__ cosT,
                                                   const float* __restrict__ sinT,
                                                   const uint4* __restrict__ Apk,
                                                   float* __restrict__ out) {
    __shared__ float trg[4][68];                                // c1,s1,c0,s0
    __shared__ __align__(16) unsigned short F1h[16 * 65 * 8];   // 16640 B
    __shared__ __align__(16) unsigned short F1l[16 * 65 * 8];   // 16640 B
    __shared__ float red[16][16];                               // 1024 B

    int tid = threadIdx.x;
    int w0 = blockIdx.x * 64;
    int b  = blockIdx.y;
    int lane = tid & 63;
    int wave = tid >> 6;
    int wb = tid & 63;
    int wu = __builtin_amdgcn_readfirstlane(wave);   // scalar wave id -> SALU digit chain

    // stage trig rows once (coalesced)
    for (int p = tid; p < 68; p += 256) {
        int pos = w0 + p;
        bool ok = pos < L_SZ;
        trg[0][p] = ok ? cosT[b * 8192 + 4096 + pos] : 0.f;
        trg[1][p] = ok ? sinT[b * 8192 + 4096 + pos] : 0.f;
        trg[2][p] = ok ? cosT[b * 8192 + pos] : 0.f;
        trg[3][p] = ok ? sinT[b * 8192 + pos] : 0.f;
    }

    f32x4 acc[4][4];
    #pragma unroll
    for (int ut = 0; ut < 4; ++ut)
        #pragma unroll
        for (int wt = 0; wt < 4; ++wt)
            acc[ut][wt] = (f32x4){0.f, 0.f, 0.f, 0.f};

    __syncthreads();

    float c1r[5], s1r[5];
    #pragma unroll
    for (int k = 0; k < 5; ++k) { c1r[k] = trg[0][wb + k]; s1r[k] = trg[1][wb + k]; }

    const uint4* Ahi = Apk;
    const uint4* Alo = Apk + 8192;

    #pragma unroll 1
    for (int h = 0; h < 2; ++h) {
        if (h) __syncthreads();
        // ---- build F1 half h: 32 v per thread, scalar digit walk ----
        {
            int gv = h * 128 + wu * 32;                 // SGPR
            int t0 = gv / 81; int rr = gv - t0 * 81;
            int t1 = rr / 27; rr -= t1 * 27;
            int t2 = rr / 9;  rr -= t2 * 9;
            int t3 = rr / 3;  int t4 = rr - t3 * 3;
            float g0 = sel3(t0, c1r[0], s1r[0]);
            float g1 = sel3(t1, c1r[1], s1r[1]);
            float g2 = sel3(t2, c1r[2], s1r[2]);
            float g3 = sel3(t3, c1r[3], s1r[3]);
            float p0123 = g0 * g1 * g2 * g3;
            #pragma unroll
            for (int p8 = 0; p8 < 4; ++p8) {
                unsigned hw[4], lw[4];
                float prevh, prevl;
                #pragma unroll
                for (int i = 0; i < 8; ++i) {
                    int gvv = gv + p8 * 8 + i;          // SGPR
                    float val = p0123 * sel3(t4, c1r[4], s1r[4]);
                    if (gvv >= U3) val = 0.f;           // scalar cond
                    unsigned uxv = __float_as_uint(val);
                    float hf = __uint_as_float(uxv & 0xFFFF0000u);
                    float lf = val - hf;
                    if (i & 1) {
                        hw[i >> 1] = __byte_perm(__float_as_uint(prevh), __float_as_uint(hf), 0x7632);
                        lw[i >> 1] = __byte_perm(__float_as_uint(prevl), __float_as_uint(lf), 0x7632);
                    } else { prevh = hf; prevl = lf; }
                    // scalar base-3 carry walk
                    if (++t4 == 3) { t4 = 0;
                        if (++t3 == 3) { t3 = 0;
                            if (++t2 == 3) { t2 = 0;
                                if (++t1 == 3) { t1 = 0; ++t0; g0 = sel3(t0, c1r[0], s1r[0]); }
                                g1 = sel3(t1, c1r[1], s1r[1]);
                            }
                            g2 = sel3(t2, c1r[2], s1r[2]);
                        }
                        g3 = sel3(t3, c1r[3], s1r[3]);
                        p0123 = g0 * g1 * g2 * g3;
                    }
                }
                int vp = wu * 4 + p8;
                *(uint4*)&F1h[(vp * 65 + wb) * 8] = make_uint4(hw[0], hw[1], hw[2], hw[3]);
                *(uint4*)&F1l[(vp * 65 + wb) * 8] = make_uint4(lw[0], lw[1], lw[2], lw[3]);
            }
        }
        __syncthreads();

        // ---- MFMA over this half's 4 K-steps ----
        #pragma unroll
        for (int kl = 0; kl < 4; ++kl) {
            int ks = h * 4 + kl;
            uint4 a_h[4], a_l[4];
            #pragma unroll
            for (int ut = 0; ut < 4; ++ut) {
                int idx = ((wave * 4 + ut) * 8 + ks) * 64 + lane;
                a_h[ut] = Ahi[idx];
                a_l[ut] = Alo[idx];
            }
            int vp = kl * 4 + (lane >> 4);
            #pragma unroll
            for (int wt = 0; wt < 4; ++wt) {
                int off = (vp * 65 + wt * 16 + (lane & 15)) * 8;
                uint4 b_h = *(const uint4*)&F1h[off];
                uint4 b_l = *(const uint4*)&F1l[off];
                bf16x8 bh = __builtin_bit_cast(bf16x8, b_h);
                bf16x8 bl = __builtin_bit_cast(bf16x8, b_l);
                #pragma unroll
                for (int ut = 0; ut < 4; ++ut) {
                    bf16x8 ah = __builtin_bit_cast(bf16x8, a_h[ut]);
                    bf16x8 al = __builtin_bit_cast(bf16x8, a_l[ut]);
                    acc[ut][wt] = __builtin_amdgcn_mfma_f32_16x16x32_bf16(ah, bh, acc[ut][wt], 0, 0, 0);
                    acc[ut][wt] = __builtin_amdgcn_mfma_f32_16x16x32_bf16(ah, bl, acc[ut][wt], 0, 0, 0);
                    acc[ut][wt] = __builtin_amdgcn_mfma_f32_16x16x32_bf16(al, bh, acc[ut][wt], 0, 0, 0);
                }
            }
        }
    }

    // ---- epilogue: z[w] = sum_u F0[u,w]*G[u,w], F0 in registers from LDS trg ----
    int c = lane & 15;
    float c0r[4][5], s0r[4][5];
    #pragma unroll
    for (int wt = 0; wt < 4; ++wt)
        #pragma unroll
        for (int k = 0; k < 5; ++k) {
            c0r[wt][k] = trg[2][wt * 16 + c + k];
            s0r[wt][k] = trg[3][wt * 16 + c + k];
        }
    float zcol[4] = {0.f, 0.f, 0.f, 0.f};
    #pragma unroll
    for (int ut = 0; ut < 4; ++ut) {
        int ubase = wave * 64 + ut * 16 + ((lane >> 4) << 2);
        #pragma unroll
        for (int r = 0; r < 4; ++r) {
            int u = ubase + r;
            int t0 = u / 81; int rr = u - t0 * 81;
            int t1 = rr / 27; rr -= t1 * 27;
            int t2 = rr / 9;  rr -= t2 * 9;
            int t3 = rr / 3;  int t4 = rr - t3 * 3;
            #pragma unroll
            for (int wt = 0; wt < 4; ++wt) {
                float f = sel3(t0, c0r[wt][0], s0r[wt][0]) * sel3(t1, c0r[wt][1], s0r[wt][1])
                        * sel3(t2, c0r[wt][2], s0r[wt][2]) * sel3(t3, c0r[wt][3], s0r[wt][3])
                        * sel3(t4, c0r[wt][4], s0r[wt][4]);
                zcol[wt] += f * acc[ut][wt][r];
            }
        }
    }

    // ---- reduce over u-groups ----
    #pragma unroll
    for (int wt = 0; wt < 4; ++wt) {
        float v = zcol[wt];
        v += __shfl_xor(v, 16, 64);
        v += __shfl_xor(v, 32, 64);
        if ((lane >> 4) == 0) red[wave * 4 + wt][lane] = v;
    }
    __syncthreads();
    if (tid < 64) {
        int wt = tid >> 4, cc = tid & 15;
        float z = red[0 * 4 + wt][cc] + red[1 * 4 + wt][cc]
                + red[2 * 4 + wt][cc] + red[3 * 4 + wt][cc];
        int w = wt * 16 + cc;
        if (w0 + w < NWIN) out[b * NWIN + w0 + w] = z;
    }
}

extern "C" void kernel_launch(void* const* d_in, const int* in_sizes, int n_in,
                              void* d_out, int out_size, void* d_ws, size_t ws_size,
                              hipStream_t stream) {
    const float* x     = (const float*)d_in[0];
    const float* E     = (const float*)d_in[1];
    const float* theta = (const float*)d_in[2];
    float* out = (float*)d_out;
    float* ws = (float*)d_ws;

    float* cosT = ws + COS_OFF;
    float* sinT = ws + SIN_OFF;
    float* Y    = ws + Y_OFF;
    float* M    = ws + M_OFF;
    float* CT   = ws + CT_OFF;
    uint4* Apk  = (uint4*)(ws + APK_OFF);
    float* Mx   = ws + EXTRA_OFF;

    size_t need4 = (size_t)(EXTRA_OFF + 3 * 1048576) * 4;
    size_t need2 = (size_t)(EXTRA_OFF + 1 * 1048576) * 4;
    int S = (ws_size >= need4) ? 4 : ((ws_size >= need2) ? 2 : 1);

    trig_ker<<<512, 256, 0, stream>>>(x, cosT, sinT);
    y_ker<<<2048, 256, 0, stream>>>(E, theta, Y);
    mgemm_ker<<<dim3(136, 1, S), 256, 0, stream>>>(E, Y, M, Mx);
    cwht_ker<<<1024, 256, 0, stream>>>(M, Mx, S, CT);
    apack_ker<<<32, 256, 0, stream>>>(CT, Apk);
    main_ker<<<dim3(64, 16), 256, 0, stream>>>(cosT, sinT, Apk, out);
}

// Round 9
// 93.634 us; speedup vs baseline: 1.2752x; 1.0662x over previous
//
#include <hip/hip_runtime.h>
#include <math.h>

// Problem constants
#define B_SZ   16
#define L_SZ   4096
#define NWIN   4092      // (4096-5)/1+1
#define U3     243       // 3^5
#define UPAD   256

// ws layout (float offsets): Apk | M | M partials
#define APK_OFF 0                         // 16384 uint4 = 65536 floats (hi 8192, lo 8192)
#define M_OFF   65536
#define EXTRA_OFF (M_OFF + 1048576)       // K-split partial buffers

typedef __attribute__((ext_vector_type(8))) __bf16 bf16x8;
typedef __attribute__((ext_vector_type(4))) float f32x4;

__device__ __forceinline__ float sel3(int t, float c, float s) {
    return t == 0 ? 1.0f : (t == 1 ? c : s);
}

// ---------------- M = E^T (G⊗I) E  (G applied on the fly; symmetric upper-tri; TILE-32 out) ----
// element (r,c) stored at [((r>>5)*32 + (c>>5))*1024 + (r&31)*32 + (c&31)]
__global__ __launch_bounds__(256, 2) void mgemm_ker(const float* __restrict__ E,
                                                    const float* __restrict__ theta,
                                                    float* __restrict__ M,
                                                    float* __restrict__ Mp_extra) {
    __shared__ float Es[16][64];
    __shared__ float Ys[16][64];
    int t = blockIdx.x;
    int bj = 0;
    while (t >= 16 - bj) { t -= 16 - bj; ++bj; }
    int bk = bj + t;
    int ks = blockIdx.z;
    int tid = threadIdx.x;
    int tx = tid & 15, ty = tid >> 4;
    int lr = tid >> 4, lc = (tid & 15) * 4;
    float th = theta[0];
    float st, ct;
    __sincosf(th, &st, &ct);
    float acc[4][4];
    #pragma unroll
    for (int i = 0; i < 4; ++i)
        #pragma unroll
        for (int j = 0; j < 4; ++j) acc[i][j] = 0.f;

    int kchunk = 1024 / gridDim.z;
    int k0 = ks * kchunk;
    for (int d0 = k0; d0 < k0 + kchunk; d0 += 16) {
        bool hi = d0 >= 512;                 // 512 boundary is chunk-aligned
        float4 e = *(const float4*)&E[(d0 + lr) * 1024 + bj * 64 + lc];
        float4 q = *(const float4*)&E[(d0 + lr) * 1024 + bk * 64 + lc];
        int dp = hi ? (d0 - 512) : (d0 + 512);
        float4 p = *(const float4*)&E[(dp + lr) * 1024 + bk * 64 + lc];
        float4 y;
        if (!hi) {   // Y[d] = ct*E[d] - st*E[d+512]
            y.x = ct * q.x - st * p.x; y.y = ct * q.y - st * p.y;
            y.z = ct * q.z - st * p.z; y.w = ct * q.w - st * p.w;
        } else {     // Y[d] = -st*E[d-512] - ct*E[d]
            y.x = -st * p.x - ct * q.x; y.y = -st * p.y - ct * q.y;
            y.z = -st * p.z - ct * q.z; y.w = -st * p.w - ct * q.w;
        }
        __syncthreads();
        *(float4*)&Es[lr][lc] = e;
        *(float4*)&Ys[lr][lc] = y;
        __syncthreads();
        #pragma unroll
        for (int dd = 0; dd < 16; ++dd) {
            float4 a = *(const float4*)&Es[dd][ty * 4];
            float4 bv = *(const float4*)&Ys[dd][tx * 4];
            acc[0][0] += a.x * bv.x; acc[0][1] += a.x * bv.y; acc[0][2] += a.x * bv.z; acc[0][3] += a.x * bv.w;
            acc[1][0] += a.y * bv.x; acc[1][1] += a.y * bv.y; acc[1][2] += a.y * bv.z; acc[1][3] += a.y * bv.w;
            acc[2][0] += a.z * bv.x; acc[2][1] += a.z * bv.y; acc[2][2] += a.z * bv.z; acc[2][3] += a.z * bv.w;
            acc[3][0] += a.w * bv.x; acc[3][1] += a.w * bv.y; acc[3][2] += a.w * bv.z; acc[3][3] += a.w * bv.w;
        }
    }
    float* dst = (ks == 0) ? M : (Mp_extra + (ks - 1) * 1048576);
    int cb = bk * 64 + tx * 4;
    int kh = cb >> 5, kl = cb & 31;
    #pragma unroll
    for (int i = 0; i < 4; ++i) {
        int r = bj * 64 + ty * 4 + i;
        int jh = r >> 5, jl = r & 31;
        float4 rv = make_float4(acc[i][0], acc[i][1], acc[i][2], acc[i][3]);
        *(float4*)&dst[((jh * 32 + kh) * 32 + jl) * 32 + kl] = rv;
    }
}

// ---------------- C via WHT (shfl stages 0-5, 1 LDS round for 6-7, in-reg 8-9),
//                  scattering bf16 hi/lo DIRECTLY into Apk fragment layout ----------------
__global__ __launch_bounds__(256) void cwht_ker(const float* __restrict__ M,
                                                const float* __restrict__ Mp_extra,
                                                int S,
                                                unsigned short* __restrict__ ApkH) {
    __shared__ float D[1024];
    int mx = blockIdx.x;
    int mxh = mx >> 5, mxl = mx & 31;
    int tid = threadIdx.x;
    float v[4];
    #pragma unroll
    for (int k = 0; k < 4; ++k) {
        int j = tid + k * 256;
        int jh = j >> 5, jl = j & 31;
        int kh = jh ^ mxh, kl = jl ^ mxl;
        int off;
        if ((jh >> 1) <= (kh >> 1)) off = ((jh * 32 + kh) * 32 + jl) * 32 + kl;
        else                        off = ((kh * 32 + jh) * 32 + kl) * 32 + jl;  // symmetric image
        float t = M[off];
        for (int s = 1; s < S; ++s) t += Mp_extra[(s - 1) * 1048576 + off];
        v[k] = t;
    }
    // stages 0..5: lane bits via shfl_xor
    #pragma unroll
    for (int s = 0; s < 6; ++s) {
        int bit = (tid >> s) & 1;
        #pragma unroll
        for (int k = 0; k < 4; ++k) {
            float p = __shfl_xor(v[k], 1 << s, 64);
            v[k] = bit ? (p - v[k]) : (v[k] + p);
        }
    }
    // stages 6,7: wave bits via one LDS round
    #pragma unroll
    for (int k = 0; k < 4; ++k) D[tid + k * 256] = v[k];
    __syncthreads();
    {
        int b6 = (tid >> 6) & 1, b7 = (tid >> 7) & 1;
        #pragma unroll
        for (int k = 0; k < 4; ++k) {
            float p64  = D[(tid ^ 64)  + k * 256];
            float p128 = D[(tid ^ 128) + k * 256];
            float p192 = D[(tid ^ 192) + k * 256];
            float ta = b6 ? (p64 - v[k])   : (v[k] + p64);
            float tb = b6 ? (p192 - p128)  : (p128 + p192);
            v[k] = b7 ? (tb - ta) : (ta + tb);
        }
    }
    // stages 8,9: k bits in-register
    {
        float a0 = v[0] + v[1], a1 = v[0] - v[1], a2 = v[2] + v[3], a3 = v[2] - v[3];
        v[0] = a0 + a2; v[1] = a1 + a3; v[2] = a0 - a2; v[3] = a1 - a3;
    }
    // scatter into Apk layout (pad regions pre-zeroed by memset)
    #pragma unroll
    for (int k = 0; k < 4; ++k) {
        int mz = tid + k * 256;
        if (mz & mx) continue;
        int u = 0, vv = 0;
        #pragma unroll
        for (int i = 0; i < 5; ++i) {
            int bit = 9 - i;
            int tt = ((mx >> bit) & 1) ? 2 : (((mz >> bit) & 1) ? 1 : 0);
            u = u * 3 + tt;
        }
        #pragma unroll
        for (int i = 5; i < 10; ++i) {
            int bit = 9 - i;
            int tt = ((mx >> bit) & 1) ? 2 : (((mz >> bit) & 1) ? 1 : 0);
            vv = vv * 3 + tt;
        }
        float val = v[k] * (1.0f / 1024.0f);
        unsigned hh = __float_as_uint(val) & 0xFFFF0000u;        // truncation split
        float lf = val - __uint_as_float(hh);
        unsigned ll = __float_as_uint(lf) >> 16;
        int idx = (((u >> 4) * 8 + (vv >> 5)) * 64 + ((u & 15) | (((vv >> 3) & 3) << 4))) * 8 + (vv & 7);
        ApkH[idx] = (unsigned short)(hh >> 16);
        ApkH[idx + 65536] = (unsigned short)ll;                  // lo block = +8192 uint4
    }
}

// ---------------- main: 64 windows/block, MFMA 16x16x32 bf16 3-term split ----------------
// Trig computed in-kernel from x (no trig tables). Two-phase F1, scalarized digit chain,
// register-F0 epilogue from LDS trg. 4 barriers.
__global__ __launch_bounds__(256, 4) void main_ker(const float* __restrict__ x,
                                                   const uint4* __restrict__ Apk,
                                                   float* __restrict__ out) {
    __shared__ float trg[4][68];                                // c1,s1,c0,s0
    __shared__ __align__(16) unsigned short F1h[16 * 65 * 8];   // 16640 B
    __shared__ __align__(16) unsigned short F1l[16 * 65 * 8];   // 16640 B
    __shared__ float red[16][16];                               // 1024 B

    int tid = threadIdx.x;
    int w0 = blockIdx.x * 64;
    int b  = blockIdx.y;
    int lane = tid & 63;
    int wave = tid >> 6;
    int wb = tid & 63;
    int wu = __builtin_amdgcn_readfirstlane(wave);   // scalar wave id -> SALU digit chain

    // stage trig rows once: sincos straight from x
    for (int p = tid; p < 68; p += 256) {
        int pos = w0 + p;
        bool ok = pos < L_SZ;
        float x1 = ok ? x[b * 8192 + 4096 + pos] : 0.f;
        float x0 = ok ? x[b * 8192 + pos] : 0.f;
        float c1v, s1v, c0v, s0v;
        __sincosf(x1, &s1v, &c1v);
        __sincosf(x0, &s0v, &c0v);
        if (!ok) { c1v = 0.f; s1v = 0.f; c0v = 0.f; s0v = 0.f; }
        trg[0][p] = c1v; trg[1][p] = s1v; trg[2][p] = c0v; trg[3][p] = s0v;
    }

    f32x4 acc[4][4];
    #pragma unroll
    for (int ut = 0; ut < 4; ++ut)
        #pragma unroll
        for (int wt = 0; wt < 4; ++wt)
            acc[ut][wt] = (f32x4){0.f, 0.f, 0.f, 0.f};

    __syncthreads();

    float c1r[5], s1r[5];
    #pragma unroll
    for (int k = 0; k < 5; ++k) { c1r[k] = trg[0][wb + k]; s1r[k] = trg[1][wb + k]; }

    const uint4* Ahi = Apk;
    const uint4* Alo = Apk + 8192;

    #pragma unroll 1
    for (int h = 0; h < 2; ++h) {
        if (h) __syncthreads();
        // ---- build F1 half h: 32 v per thread, scalar digit walk ----
        {
            int gv = h * 128 + wu * 32;                 // SGPR
            int t0 = gv / 81; int rr = gv - t0 * 81;
            int t1 = rr / 27; rr -= t1 * 27;
            int t2 = rr / 9;  rr -= t2 * 9;
            int t3 = rr / 3;  int t4 = rr - t3 * 3;
            float g0 = sel3(t0, c1r[0], s1r[0]);
            float g1 = sel3(t1, c1r[1], s1r[1]);
            float g2 = sel3(t2, c1r[2], s1r[2]);
            float g3 = sel3(t3, c1r[3], s1r[3]);
            float p0123 = g0 * g1 * g2 * g3;
            #pragma unroll
            for (int p8 = 0; p8 < 4; ++p8) {
                unsigned hw[4], lw[4];
                float prevh, prevl;
                #pragma unroll
                for (int i = 0; i < 8; ++i) {
                    int gvv = gv + p8 * 8 + i;          // SGPR
                    float val = p0123 * sel3(t4, c1r[4], s1r[4]);
                    if (gvv >= U3) val = 0.f;           // scalar cond
                    unsigned uxv = __float_as_uint(val);
                    float hf = __uint_as_float(uxv & 0xFFFF0000u);
                    float lf = val - hf;
                    if (i & 1) {
                        hw[i >> 1] = __byte_perm(__float_as_uint(prevh), __float_as_uint(hf), 0x7632);
                        lw[i >> 1] = __byte_perm(__float_as_uint(prevl), __float_as_uint(lf), 0x7632);
                    } else { prevh = hf; prevl = lf; }
                    if (++t4 == 3) { t4 = 0;
                        if (++t3 == 3) { t3 = 0;
                            if (++t2 == 3) { t2 = 0;
                                if (++t1 == 3) { t1 = 0; ++t0; g0 = sel3(t0, c1r[0], s1r[0]); }
                                g1 = sel3(t1, c1r[1], s1r[1]);
                            }
                            g2 = sel3(t2, c1r[2], s1r[2]);
                        }
                        g3 = sel3(t3, c1r[3], s1r[3]);
                        p0123 = g0 * g1 * g2 * g3;
                    }
                }
                int vp = wu * 4 + p8;
                *(uint4*)&F1h[(vp * 65 + wb) * 8] = make_uint4(hw[0], hw[1], hw[2], hw[3]);
                *(uint4*)&F1l[(vp * 65 + wb) * 8] = make_uint4(lw[0], lw[1], lw[2], lw[3]);
            }
        }
        __syncthreads();

        // ---- MFMA over this half's 4 K-steps ----
        #pragma unroll
        for (int kl = 0; kl < 4; ++kl) {
            int ks = h * 4 + kl;
            uint4 a_h[4], a_l[4];
            #pragma unroll
            for (int ut = 0; ut < 4; ++ut) {
                int idx = ((wave * 4 + ut) * 8 + ks) * 64 + lane;
                a_h[ut] = Ahi[idx];
                a_l[ut] = Alo[idx];
            }
            int vp = kl * 4 + (lane >> 4);
            #pragma unroll
            for (int wt = 0; wt < 4; ++wt) {
                int off = (vp * 65 + wt * 16 + (lane & 15)) * 8;
                uint4 b_h = *(const uint4*)&F1h[off];
                uint4 b_l = *(const uint4*)&F1l[off];
                bf16x8 bh = __builtin_bit_cast(bf16x8, b_h);
                bf16x8 bl = __builtin_bit_cast(bf16x8, b_l);
                #pragma unroll
                for (int ut = 0; ut < 4; ++ut) {
                    bf16x8 ah = __builtin_bit_cast(bf16x8, a_h[ut]);
                    bf16x8 al = __builtin_bit_cast(bf16x8, a_l[ut]);
                    acc[ut][wt] = __builtin_amdgcn_mfma_f32_16x16x32_bf16(ah, bh, acc[ut][wt], 0, 0, 0);
                    acc[ut][wt] = __builtin_amdgcn_mfma_f32_16x16x32_bf16(ah, bl, acc[ut][wt], 0, 0, 0);
                    acc[ut][wt] = __builtin_amdgcn_mfma_f32_16x16x32_bf16(al, bh, acc[ut][wt], 0, 0, 0);
                }
            }
        }
    }

    // ---- epilogue: z[w] = sum_u F0[u,w]*G[u,w], F0 in registers from LDS trg ----
    int c = lane & 15;
    float c0r[4][5], s0r[4][5];
    #pragma unroll
    for (int wt = 0; wt < 4; ++wt)
        #pragma unroll
        for (int k = 0; k < 5; ++k) {
            c0r[wt][k] = trg[2][wt * 16 + c + k];
            s0r[wt][k] = trg[3][wt * 16 + c + k];
        }
    float zcol[4] = {0.f, 0.f, 0.f, 0.f};
    #pragma unroll
    for (int ut = 0; ut < 4; ++ut) {
        int ubase = wave * 64 + ut * 16 + ((lane >> 4) << 2);
        #pragma unroll
        for (int r = 0; r < 4; ++r) {
            int u = ubase + r;
            int t0 = u / 81; int rr = u - t0 * 81;
            int t1 = rr / 27; rr -= t1 * 27;
            int t2 = rr / 9;  rr -= t2 * 9;
            int t3 = rr / 3;  int t4 = rr - t3 * 3;
            #pragma unroll
            for (int wt = 0; wt < 4; ++wt) {
                float f = sel3(t0, c0r[wt][0], s0r[wt][0]) * sel3(t1, c0r[wt][1], s0r[wt][1])
                        * sel3(t2, c0r[wt][2], s0r[wt][2]) * sel3(t3, c0r[wt][3], s0r[wt][3])
                        * sel3(t4, c0r[wt][4], s0r[wt][4]);
                zcol[wt] += f * acc[ut][wt][r];
            }
        }
    }

    // ---- reduce over u-groups ----
    #pragma unroll
    for (int wt = 0; wt < 4; ++wt) {
        float v = zcol[wt];
        v += __shfl_xor(v, 16, 64);
        v += __shfl_xor(v, 32, 64);
        if ((lane >> 4) == 0) red[wave * 4 + wt][lane] = v;
    }
    __syncthreads();
    if (tid < 64) {
        int wt = tid >> 4, cc = tid & 15;
        float z = red[0 * 4 + wt][cc] + red[1 * 4 + wt][cc]
                + red[2 * 4 + wt][cc] + red[3 * 4 + wt][cc];
        int w = wt * 16 + cc;
        if (w0 + w < NWIN) out[b * NWIN + w0 + w] = z;
    }
}

extern "C" void kernel_launch(void* const* d_in, const int* in_sizes, int n_in,
                              void* d_out, int out_size, void* d_ws, size_t ws_size,
                              hipStream_t stream) {
    const float* x     = (const float*)d_in[0];
    const float* E     = (const float*)d_in[1];
    const float* theta = (const float*)d_in[2];
    float* out = (float*)d_out;
    float* ws = (float*)d_ws;

    uint4* Apk = (uint4*)(ws + APK_OFF);
    float* M   = ws + M_OFF;
    float* Mx  = ws + EXTRA_OFF;

    size_t need4 = (size_t)(EXTRA_OFF + 3 * 1048576) * 4;
    size_t need2 = (size_t)(EXTRA_OFF + 1 * 1048576) * 4;
    int S = (ws_size >= need4) ? 4 : ((ws_size >= need2) ? 2 : 1);

    hipMemsetAsync(Apk, 0, 16384 * sizeof(uint4), stream);   // zero pads for direct scatter
    mgemm_ker<<<dim3(136, 1, S), 256, 0, stream>>>(E, theta, M, Mx);
    cwht_ker<<<1024, 256, 0, stream>>>(M, Mx, S, (unsigned short*)Apk);
    main_ker<<<dim3(64, 16), 256, 0, stream>>>(x, Apk, out);
}

// Round 10
// 90.493 us; speedup vs baseline: 1.3195x; 1.0347x over previous
//
#include <hip/hip_runtime.h>
#include <math.h>

// Problem constants
#define B_SZ   16
#define L_SZ   4096
#define NWIN   4092      // (4096-5)/1+1
#define U3     243       // 3^5
#define UPAD   256

// ws layout (float offsets): Apk | M | M partials
#define APK_OFF 0                         // 16384 uint4 (hi 8192, lo 8192)
#define M_OFF   65536
#define EXTRA_OFF (M_OFF + 1048576)       // K-split partial buffers

typedef __attribute__((ext_vector_type(8))) __bf16 bf16x8;
typedef __attribute__((ext_vector_type(4))) float f32x4;

__device__ __forceinline__ float sel3(int t, float c, float s) {
    return t == 0 ? 1.0f : (t == 1 ? c : s);
}

// Apk fragment index for element C[u][v]
__device__ __forceinline__ int apk_idx(int u, int v) {
    return (((u >> 4) * 8 + (v >> 5)) * 64 + ((u & 15) | (((v >> 3) & 3) << 4))) * 8 + (v & 7);
}

// ---------------- M = E^T (G⊗I) E  (G applied on the fly; symmetric upper-tri; TILE-32 out) ----
__global__ __launch_bounds__(256, 2) void mgemm_ker(const float* __restrict__ E,
                                                    const float* __restrict__ theta,
                                                    float* __restrict__ M,
                                                    float* __restrict__ Mp_extra) {
    __shared__ float Es[16][64];
    __shared__ float Ys[16][64];
    int t = blockIdx.x;
    int bj = 0;
    while (t >= 16 - bj) { t -= 16 - bj; ++bj; }
    int bk = bj + t;
    int ks = blockIdx.z;
    int tid = threadIdx.x;
    int tx = tid & 15, ty = tid >> 4;
    int lr = tid >> 4, lc = (tid & 15) * 4;
    float th = theta[0];
    float st, ct;
    __sincosf(th, &st, &ct);
    float acc[4][4];
    #pragma unroll
    for (int i = 0; i < 4; ++i)
        #pragma unroll
        for (int j = 0; j < 4; ++j) acc[i][j] = 0.f;

    int kchunk = 1024 / gridDim.z;
    int k0 = ks * kchunk;
    for (int d0 = k0; d0 < k0 + kchunk; d0 += 16) {
        bool hi = d0 >= 512;                 // 512 boundary is chunk-aligned
        float4 e = *(const float4*)&E[(d0 + lr) * 1024 + bj * 64 + lc];
        float4 q = *(const float4*)&E[(d0 + lr) * 1024 + bk * 64 + lc];
        int dp = hi ? (d0 - 512) : (d0 + 512);
        float4 p = *(const float4*)&E[(dp + lr) * 1024 + bk * 64 + lc];
        float4 y;
        if (!hi) {   // Y[d] = ct*E[d] - st*E[d+512]
            y.x = ct * q.x - st * p.x; y.y = ct * q.y - st * p.y;
            y.z = ct * q.z - st * p.z; y.w = ct * q.w - st * p.w;
        } else {     // Y[d] = -st*E[d-512] - ct*E[d]
            y.x = -st * p.x - ct * q.x; y.y = -st * p.y - ct * q.y;
            y.z = -st * p.z - ct * q.z; y.w = -st * p.w - ct * q.w;
        }
        __syncthreads();
        *(float4*)&Es[lr][lc] = e;
        *(float4*)&Ys[lr][lc] = y;
        __syncthreads();
        #pragma unroll
        for (int dd = 0; dd < 16; ++dd) {
            float4 a = *(const float4*)&Es[dd][ty * 4];
            float4 bv = *(const float4*)&Ys[dd][tx * 4];
            acc[0][0] += a.x * bv.x; acc[0][1] += a.x * bv.y; acc[0][2] += a.x * bv.z; acc[0][3] += a.x * bv.w;
            acc[1][0] += a.y * bv.x; acc[1][1] += a.y * bv.y; acc[1][2] += a.y * bv.z; acc[1][3] += a.y * bv.w;
            acc[2][0] += a.z * bv.x; acc[2][1] += a.z * bv.y; acc[2][2] += a.z * bv.z; acc[2][3] += a.z * bv.w;
            acc[3][0] += a.w * bv.x; acc[3][1] += a.w * bv.y; acc[3][2] += a.w * bv.z; acc[3][3] += a.w * bv.w;
        }
    }
    float* dst = (ks == 0) ? M : (Mp_extra + (ks - 1) * 1048576);
    int cb = bk * 64 + tx * 4;
    int kh = cb >> 5, kl = cb & 31;
    #pragma unroll
    for (int i = 0; i < 4; ++i) {
        int r = bj * 64 + ty * 4 + i;
        int jh = r >> 5, jl = r & 31;
        float4 rv = make_float4(acc[i][0], acc[i][1], acc[i][2], acc[i][3]);
        *(float4*)&dst[((jh * 32 + kh) * 32 + jl) * 32 + kl] = rv;
    }
}

// ---------------- C via WHT, scattering bf16 hi/lo into Apk; mx==0 also zeroes pads ----------------
__global__ __launch_bounds__(256) void cwht_ker(const float* __restrict__ M,
                                                const float* __restrict__ Mp_extra,
                                                int S,
                                                unsigned short* __restrict__ ApkH) {
    __shared__ float D[1024];
    int mx = blockIdx.x;
    int mxh = mx >> 5, mxl = mx & 31;
    int tid = threadIdx.x;
    float v[4];
    #pragma unroll
    for (int k = 0; k < 4; ++k) {
        int j = tid + k * 256;
        int jh = j >> 5, jl = j & 31;
        int kh = jh ^ mxh, kl = jl ^ mxl;
        int off;
        if ((jh >> 1) <= (kh >> 1)) off = ((jh * 32 + kh) * 32 + jl) * 32 + kl;
        else                        off = ((kh * 32 + jh) * 32 + kl) * 32 + jl;  // symmetric image
        float t = M[off];
        for (int s = 1; s < S; ++s) t += Mp_extra[(s - 1) * 1048576 + off];
        v[k] = t;
    }
    // stages 0..5: lane bits via shfl_xor
    #pragma unroll
    for (int s = 0; s < 6; ++s) {
        int bit = (tid >> s) & 1;
        #pragma unroll
        for (int k = 0; k < 4; ++k) {
            float p = __shfl_xor(v[k], 1 << s, 64);
            v[k] = bit ? (p - v[k]) : (v[k] + p);
        }
    }
    // stages 6,7: wave bits via one LDS round
    #pragma unroll
    for (int k = 0; k < 4; ++k) D[tid + k * 256] = v[k];
    __syncthreads();
    {
        int b6 = (tid >> 6) & 1, b7 = (tid >> 7) & 1;
        #pragma unroll
        for (int k = 0; k < 4; ++k) {
            float p64  = D[(tid ^ 64)  + k * 256];
            float p128 = D[(tid ^ 128) + k * 256];
            float p192 = D[(tid ^ 192) + k * 256];
            float ta = b6 ? (p64 - v[k])   : (v[k] + p64);
            float tb = b6 ? (p192 - p128)  : (p128 + p192);
            v[k] = b7 ? (tb - ta) : (ta + tb);
        }
    }
    // stages 8,9: k bits in-register
    {
        float a0 = v[0] + v[1], a1 = v[0] - v[1], a2 = v[2] + v[3], a3 = v[2] - v[3];
        v[0] = a0 + a2; v[1] = a1 + a3; v[2] = a0 - a2; v[3] = a1 - a3;
    }
    // scatter into Apk layout
    #pragma unroll
    for (int k = 0; k < 4; ++k) {
        int mz = tid + k * 256;
        if (mz & mx) continue;
        int u = 0, vv = 0;
        #pragma unroll
        for (int i = 0; i < 5; ++i) {
            int bit = 9 - i;
            int tt = ((mx >> bit) & 1) ? 2 : (((mz >> bit) & 1) ? 1 : 0);
            u = u * 3 + tt;
        }
        #pragma unroll
        for (int i = 5; i < 10; ++i) {
            int bit = 9 - i;
            int tt = ((mx >> bit) & 1) ? 2 : (((mz >> bit) & 1) ? 1 : 0);
            vv = vv * 3 + tt;
        }
        float val = v[k] * (1.0f / 1024.0f);
        unsigned hh = __float_as_uint(val) & 0xFFFF0000u;        // truncation split
        float lf = val - __uint_as_float(hh);
        unsigned ll = __float_as_uint(lf) >> 16;
        int idx = apk_idx(u, vv);
        ApkH[idx] = (unsigned short)(hh >> 16);
        ApkH[idx + 65536] = (unsigned short)ll;
    }
    // zero pad entries (u>=243 or v>=243); disjoint from all scatter writes
    if (mx == 0) {
        for (int e = tid; e < 13 * 256; e += 256) {          // u in [243,256), all v
            int u = 243 + (e >> 8), vv = e & 255;
            int idx = apk_idx(u, vv);
            ApkH[idx] = 0; ApkH[idx + 65536] = 0;
        }
        for (int e = tid; e < 243 * 13; e += 256) {          // u < 243, v in [243,256)
            int u = e / 13, vv = 243 + (e - (e / 13) * 13);
            int idx = apk_idx(u, vv);
            ApkH[idx] = 0; ApkH[idx + 65536] = 0;
        }
    }
}

// ---------------- main: 64 windows/block, MFMA 16x16x32 bf16 3-term split ----------------
// F1 two-phase scalar-walk build; F0 epilogue ALSO via LDS scalar-walk table (arena reused).
__global__ __launch_bounds__(256, 4) void main_ker(const float* __restrict__ x,
                                                   const uint4* __restrict__ Apk,
                                                   float* __restrict__ out) {
    __shared__ float trg[4][68];                                // c1,s1,c0,s0
    __shared__ __align__(16) unsigned char arena[33280];        // F1h|F1l, then F0[128][65] f32
    unsigned short* F1h = (unsigned short*)arena;               // 16640 B
    unsigned short* F1l = (unsigned short*)(arena + 16640);     // 16640 B
    float* F0 = (float*)arena;                                  // 128*65*4 = 33280 B
    __shared__ float red[16][16];                               // 1024 B

    int tid = threadIdx.x;
    int w0 = blockIdx.x * 64;
    int b  = blockIdx.y;
    int lane = tid & 63;
    int wave = tid >> 6;
    int wb = tid & 63;
    int wu = __builtin_amdgcn_readfirstlane(wave);   // scalar wave id -> SALU digit chains

    // stage trig rows once: sincos straight from x
    for (int p = tid; p < 68; p += 256) {
        int pos = w0 + p;
        bool ok = pos < L_SZ;
        float x1 = ok ? x[b * 8192 + 4096 + pos] : 0.f;
        float x0 = ok ? x[b * 8192 + pos] : 0.f;
        float c1v, s1v, c0v, s0v;
        __sincosf(x1, &s1v, &c1v);
        __sincosf(x0, &s0v, &c0v);
        if (!ok) { c1v = 0.f; s1v = 0.f; c0v = 0.f; s0v = 0.f; }
        trg[0][p] = c1v; trg[1][p] = s1v; trg[2][p] = c0v; trg[3][p] = s0v;
    }

    f32x4 acc[4][4];
    #pragma unroll
    for (int ut = 0; ut < 4; ++ut)
        #pragma unroll
        for (int wt = 0; wt < 4; ++wt)
            acc[ut][wt] = (f32x4){0.f, 0.f, 0.f, 0.f};

    __syncthreads();

    float c1r[5], s1r[5];
    #pragma unroll
    for (int k = 0; k < 5; ++k) { c1r[k] = trg[0][wb + k]; s1r[k] = trg[1][wb + k]; }

    const uint4* Ahi = Apk;
    const uint4* Alo = Apk + 8192;

    #pragma unroll 1
    for (int h = 0; h < 2; ++h) {
        if (h) __syncthreads();
        // ---- build F1 half h: 32 v per thread, scalar digit walk (pad rows may hold garbage:
        //      A's v>=243 columns are zero, so they never contribute) ----
        {
            int gv = h * 128 + wu * 32;                 // SGPR
            int t0 = gv / 81; int rr = gv - t0 * 81;
            int t1 = rr / 27; rr -= t1 * 27;
            int t2 = rr / 9;  rr -= t2 * 9;
            int t3 = rr / 3;  int t4 = rr - t3 * 3;
            float g0 = sel3(t0, c1r[0], s1r[0]);
            float g1 = sel3(t1, c1r[1], s1r[1]);
            float g2 = sel3(t2, c1r[2], s1r[2]);
            float g3 = sel3(t3, c1r[3], s1r[3]);
            float p0123 = g0 * g1 * g2 * g3;
            #pragma unroll
            for (int p8 = 0; p8 < 4; ++p8) {
                unsigned hw[4], lw[4];
                float prevh, prevl;
                #pragma unroll
                for (int i = 0; i < 8; ++i) {
                    float val = p0123 * sel3(t4, c1r[4], s1r[4]);
                    unsigned uxv = __float_as_uint(val);
                    float hf = __uint_as_float(uxv & 0xFFFF0000u);
                    float lf = val - hf;
                    if (i & 1) {
                        hw[i >> 1] = __byte_perm(__float_as_uint(prevh), __float_as_uint(hf), 0x7632);
                        lw[i >> 1] = __byte_perm(__float_as_uint(prevl), __float_as_uint(lf), 0x7632);
                    } else { prevh = hf; prevl = lf; }
                    if (++t4 == 3) { t4 = 0;
                        if (++t3 == 3) { t3 = 0;
                            if (++t2 == 3) { t2 = 0;
                                if (++t1 == 3) { t1 = 0; ++t0; g0 = sel3(t0, c1r[0], s1r[0]); }
                                g1 = sel3(t1, c1r[1], s1r[1]);
                            }
                            g2 = sel3(t2, c1r[2], s1r[2]);
                        }
                        g3 = sel3(t3, c1r[3], s1r[3]);
                        p0123 = g0 * g1 * g2 * g3;
                    }
                }
                int vp = wu * 4 + p8;
                *(uint4*)&F1h[(vp * 65 + wb) * 8] = make_uint4(hw[0], hw[1], hw[2], hw[3]);
                *(uint4*)&F1l[(vp * 65 + wb) * 8] = make_uint4(lw[0], lw[1], lw[2], lw[3]);
            }
        }
        __syncthreads();

        // ---- MFMA over this half's 4 K-steps ----
        #pragma unroll
        for (int kl = 0; kl < 4; ++kl) {
            int ks = h * 4 + kl;
            uint4 a_h[4], a_l[4];
            #pragma unroll
            for (int ut = 0; ut < 4; ++ut) {
                int idx = ((wave * 4 + ut) * 8 + ks) * 64 + lane;
                a_h[ut] = Ahi[idx];
                a_l[ut] = Alo[idx];
            }
            int vp = kl * 4 + (lane >> 4);
            #pragma unroll
            for (int wt = 0; wt < 4; ++wt) {
                int off = (vp * 65 + wt * 16 + (lane & 15)) * 8;
                uint4 b_h = *(const uint4*)&F1h[off];
                uint4 b_l = *(const uint4*)&F1l[off];
                bf16x8 bh = __builtin_bit_cast(bf16x8, b_h);
                bf16x8 bl = __builtin_bit_cast(bf16x8, b_l);
                #pragma unroll
                for (int ut = 0; ut < 4; ++ut) {
                    bf16x8 ah = __builtin_bit_cast(bf16x8, a_h[ut]);
                    bf16x8 al = __builtin_bit_cast(bf16x8, a_l[ut]);
                    acc[ut][wt] = __builtin_amdgcn_mfma_f32_16x16x32_bf16(ah, bh, acc[ut][wt], 0, 0, 0);
                    acc[ut][wt] = __builtin_amdgcn_mfma_f32_16x16x32_bf16(ah, bl, acc[ut][wt], 0, 0, 0);
                    acc[ut][wt] = __builtin_amdgcn_mfma_f32_16x16x32_bf16(al, bh, acc[ut][wt], 0, 0, 0);
                }
            }
        }
    }

    // ---- epilogue: z[w] = sum_u F0[u,w]*G[u,w] via LDS F0 table (arena reused),
    //      two u-half phases; F0 built by the same scalar-carry walk as F1 ----
    int c = lane & 15;
    float c0b[5], s0b[5];
    #pragma unroll
    for (int k = 0; k < 5; ++k) { c0b[k] = trg[2][wb + k]; s0b[k] = trg[3][wb + k]; }
    float zcol[4] = {0.f, 0.f, 0.f, 0.f};

    __syncthreads();                         // all F1 reads complete before arena overwrite
    #pragma unroll 1
    for (int hp = 0; hp < 2; ++hp) {
        if (hp) __syncthreads();             // hp=0 reads done before rebuild
        {
            int gu = hp * 128 + wu * 32;     // SGPR
            int t0 = gu / 81; int rr = gu - t0 * 81;
            int t1 = rr / 27; rr -= t1 * 27;
            int t2 = rr / 9;  rr -= t2 * 9;
            int t3 = rr / 3;  int t4 = rr - t3 * 3;
            float g0 = sel3(t0, c0b[0], s0b[0]);
            float g1 = sel3(t1, c0b[1], s0b[1]);
            float g2 = sel3(t2, c0b[2], s0b[2]);
            float g3 = sel3(t3, c0b[3], s0b[3]);
            float p0123 = g0 * g1 * g2 * g3;
            #pragma unroll
            for (int s = 0; s < 32; ++s) {
                float val = p0123 * sel3(t4, c0b[4], s0b[4]);   // u>=243 garbage is x0-bounded, acc rows are 0
                F0[(wu * 32 + s) * 65 + wb] = val;
                if (++t4 == 3) { t4 = 0;
                    if (++t3 == 3) { t3 = 0;
                        if (++t2 == 3) { t2 = 0;
                            if (++t1 == 3) { t1 = 0; ++t0; g0 = sel3(t0, c0b[0], s0b[0]); }
                            g1 = sel3(t1, c0b[1], s0b[1]);
                        }
                        g2 = sel3(t2, c0b[2], s0b[2]);
                    }
                    g3 = sel3(t3, c0b[3], s0b[3]);
                    p0123 = g0 * g1 * g2 * g3;
                }
            }
        }
        __syncthreads();
        if ((wave >> 1) == hp) {             // waves whose u-band lies in this half
            int wloc = wave & 1;
            int qb = (lane >> 4) << 2;
            #pragma unroll
            for (int ut = 0; ut < 4; ++ut) {
                #pragma unroll
                for (int r = 0; r < 4; ++r) {
                    int uloc = wloc * 64 + ut * 16 + qb + r;
                    #pragma unroll
                    for (int wt = 0; wt < 4; ++wt)
                        zcol[wt] += F0[uloc * 65 + wt * 16 + c] * acc[ut][wt][r];
                }
            }
        }
    }

    // ---- reduce over u-groups: in-wave (lane>>4), then across 4 waves via LDS ----
    #pragma unroll
    for (int wt = 0; wt < 4; ++wt) {
        float v = zcol[wt];
        v += __shfl_xor(v, 16, 64);
        v += __shfl_xor(v, 32, 64);
        if ((lane >> 4) == 0) red[wave * 4 + wt][lane] = v;
    }
    __syncthreads();
    if (tid < 64) {
        int wt = tid >> 4, cc = tid & 15;
        float z = red[0 * 4 + wt][cc] + red[1 * 4 + wt][cc]
                + red[2 * 4 + wt][cc] + red[3 * 4 + wt][cc];
        int w = wt * 16 + cc;
        if (w0 + w < NWIN) out[b * NWIN + w0 + w] = z;
    }
}

extern "C" void kernel_launch(void* const* d_in, const int* in_sizes, int n_in,
                              void* d_out, int out_size, void* d_ws, size_t ws_size,
                              hipStream_t stream) {
    const float* x     = (const float*)d_in[0];
    const float* E     = (const float*)d_in[1];
    const float* theta = (const float*)d_in[2];
    float* out = (float*)d_out;
    float* ws = (float*)d_ws;

    uint4* Apk = (uint4*)(ws + APK_OFF);
    float* M   = ws + M_OFF;
    float* Mx  = ws + EXTRA_OFF;

    size_t need4 = (size_t)(EXTRA_OFF + 3 * 1048576) * 4;
    size_t need2 = (size_t)(EXTRA_OFF + 1 * 1048576) * 4;
    int S = (ws_size >= need4) ? 4 : ((ws_size >= need2) ? 2 : 1);

    mgemm_ker<<<dim3(136, 1, S), 256, 0, stream>>>(E, theta, M, Mx);
    cwht_ker<<<1024, 256, 0, stream>>>(M, Mx, S, (unsigned short*)Apk);
    main_ker<<<dim3(64, 16), 256, 0, stream>>>(x, Apk, out);
}

// Round 11
// 86.160 us; speedup vs baseline: 1.3858x; 1.0503x over previous
//
#include <hip/hip_runtime.h>
#include <math.h>

// Problem constants
#define B_SZ   16
#define L_SZ   4096
#define NWIN   4092      // (4096-5)/1+1
#define U3     243       // 3^5
#define UPAD   256

// ws layout (float offsets): Apk | M | M partials
#define APK_OFF 0                         // 16384 uint4 (hi 8192, lo 8192)
#define M_OFF   65536
#define EXTRA_OFF (M_OFF + 1048576)       // K-split partial buffers

typedef __attribute__((ext_vector_type(8))) __bf16 bf16x8;
typedef __attribute__((ext_vector_type(4))) float f32x4;

__device__ __forceinline__ float sel3(int t, float c, float s) {
    return t == 0 ? 1.0f : (t == 1 ? c : s);
}

// Apk fragment index for element C[u][v]
__device__ __forceinline__ int apk_idx(int u, int v) {
    return (((u >> 4) * 8 + (v >> 5)) * 64 + ((u & 15) | (((v >> 3) & 3) << 4))) * 8 + (v & 7);
}

// ---------------- M = E^T (G⊗I) E  (G applied on the fly; symmetric upper-tri; TILE-32 out) ----
__global__ __launch_bounds__(256, 2) void mgemm_ker(const float* __restrict__ E,
                                                    const float* __restrict__ theta,
                                                    float* __restrict__ M,
                                                    float* __restrict__ Mp_extra) {
    __shared__ float Es[16][64];
    __shared__ float Ys[16][64];
    int t = blockIdx.x;
    int bj = 0;
    while (t >= 16 - bj) { t -= 16 - bj; ++bj; }
    int bk = bj + t;
    int ks = blockIdx.z;
    int tid = threadIdx.x;
    int tx = tid & 15, ty = tid >> 4;
    int lr = tid >> 4, lc = (tid & 15) * 4;
    float th = theta[0];
    float st, ct;
    __sincosf(th, &st, &ct);
    float acc[4][4];
    #pragma unroll
    for (int i = 0; i < 4; ++i)
        #pragma unroll
        for (int j = 0; j < 4; ++j) acc[i][j] = 0.f;

    int kchunk = 1024 / gridDim.z;
    int k0 = ks * kchunk;
    for (int d0 = k0; d0 < k0 + kchunk; d0 += 16) {
        bool hi = d0 >= 512;                 // 512 boundary is chunk-aligned
        float4 e = *(const float4*)&E[(d0 + lr) * 1024 + bj * 64 + lc];
        float4 q = *(const float4*)&E[(d0 + lr) * 1024 + bk * 64 + lc];
        int dp = hi ? (d0 - 512) : (d0 + 512);
        float4 p = *(const float4*)&E[(dp + lr) * 1024 + bk * 64 + lc];
        float4 y;
        if (!hi) {   // Y[d] = ct*E[d] - st*E[d+512]
            y.x = ct * q.x - st * p.x; y.y = ct * q.y - st * p.y;
            y.z = ct * q.z - st * p.z; y.w = ct * q.w - st * p.w;
        } else {     // Y[d] = -st*E[d-512] - ct*E[d]
            y.x = -st * p.x - ct * q.x; y.y = -st * p.y - ct * q.y;
            y.z = -st * p.z - ct * q.z; y.w = -st * p.w - ct * q.w;
        }
        __syncthreads();
        *(float4*)&Es[lr][lc] = e;
        *(float4*)&Ys[lr][lc] = y;
        __syncthreads();
        #pragma unroll
        for (int dd = 0; dd < 16; ++dd) {
            float4 a = *(const float4*)&Es[dd][ty * 4];
            float4 bv = *(const float4*)&Ys[dd][tx * 4];
            acc[0][0] += a.x * bv.x; acc[0][1] += a.x * bv.y; acc[0][2] += a.x * bv.z; acc[0][3] += a.x * bv.w;
            acc[1][0] += a.y * bv.x; acc[1][1] += a.y * bv.y; acc[1][2] += a.y * bv.z; acc[1][3] += a.y * bv.w;
            acc[2][0] += a.z * bv.x; acc[2][1] += a.z * bv.y; acc[2][2] += a.z * bv.z; acc[2][3] += a.z * bv.w;
            acc[3][0] += a.w * bv.x; acc[3][1] += a.w * bv.y; acc[3][2] += a.w * bv.z; acc[3][3] += a.w * bv.w;
        }
    }
    float* dst = (ks == 0) ? M : (Mp_extra + (ks - 1) * 1048576);
    int cb = bk * 64 + tx * 4;
    int kh = cb >> 5, kl = cb & 31;
    #pragma unroll
    for (int i = 0; i < 4; ++i) {
        int r = bj * 64 + ty * 4 + i;
        int jh = r >> 5, jl = r & 31;
        float4 rv = make_float4(acc[i][0], acc[i][1], acc[i][2], acc[i][3]);
        *(float4*)&dst[((jh * 32 + kh) * 32 + jl) * 32 + kl] = rv;
    }
}

// ---------------- C via WHT, scattering bf16 hi/lo into Apk; mx==0 also zeroes pads ----------------
__global__ __launch_bounds__(256) void cwht_ker(const float* __restrict__ M,
                                                const float* __restrict__ Mp_extra,
                                                int S,
                                                unsigned short* __restrict__ ApkH) {
    __shared__ float D[1024];
    int mx = blockIdx.x;
    int mxh = mx >> 5, mxl = mx & 31;
    int tid = threadIdx.x;
    float v[4];
    #pragma unroll
    for (int k = 0; k < 4; ++k) {
        int j = tid + k * 256;
        int jh = j >> 5, jl = j & 31;
        int kh = jh ^ mxh, kl = jl ^ mxl;
        int off;
        if ((jh >> 1) <= (kh >> 1)) off = ((jh * 32 + kh) * 32 + jl) * 32 + kl;
        else                        off = ((kh * 32 + jh) * 32 + kl) * 32 + jl;  // symmetric image
        float t = M[off];
        for (int s = 1; s < S; ++s) t += Mp_extra[(s - 1) * 1048576 + off];
        v[k] = t;
    }
    // stages 0..5: lane bits via shfl_xor
    #pragma unroll
    for (int s = 0; s < 6; ++s) {
        int bit = (tid >> s) & 1;
        #pragma unroll
        for (int k = 0; k < 4; ++k) {
            float p = __shfl_xor(v[k], 1 << s, 64);
            v[k] = bit ? (p - v[k]) : (v[k] + p);
        }
    }
    // stages 6,7: wave bits via one LDS round
    #pragma unroll
    for (int k = 0; k < 4; ++k) D[tid + k * 256] = v[k];
    __syncthreads();
    {
        int b6 = (tid >> 6) & 1, b7 = (tid >> 7) & 1;
        #pragma unroll
        for (int k = 0; k < 4; ++k) {
            float p64  = D[(tid ^ 64)  + k * 256];
            float p128 = D[(tid ^ 128) + k * 256];
            float p192 = D[(tid ^ 192) + k * 256];
            float ta = b6 ? (p64 - v[k])   : (v[k] + p64);
            float tb = b6 ? (p192 - p128)  : (p128 + p192);
            v[k] = b7 ? (tb - ta) : (ta + tb);
        }
    }
    // stages 8,9: k bits in-register
    {
        float a0 = v[0] + v[1], a1 = v[0] - v[1], a2 = v[2] + v[3], a3 = v[2] - v[3];
        v[0] = a0 + a2; v[1] = a1 + a3; v[2] = a0 - a2; v[3] = a1 - a3;
    }
    // scatter into Apk layout
    #pragma unroll
    for (int k = 0; k < 4; ++k) {
        int mz = tid + k * 256;
        if (mz & mx) continue;
        int u = 0, vv = 0;
        #pragma unroll
        for (int i = 0; i < 5; ++i) {
            int bit = 9 - i;
            int tt = ((mx >> bit) & 1) ? 2 : (((mz >> bit) & 1) ? 1 : 0);
            u = u * 3 + tt;
        }
        #pragma unroll
        for (int i = 5; i < 10; ++i) {
            int bit = 9 - i;
            int tt = ((mx >> bit) & 1) ? 2 : (((mz >> bit) & 1) ? 1 : 0);
            vv = vv * 3 + tt;
        }
        float val = v[k] * (1.0f / 1024.0f);
        unsigned hh = __float_as_uint(val) & 0xFFFF0000u;        // truncation split
        float lf = val - __uint_as_float(hh);
        unsigned ll = __float_as_uint(lf) >> 16;
        int idx = apk_idx(u, vv);
        ApkH[idx] = (unsigned short)(hh >> 16);
        ApkH[idx + 65536] = (unsigned short)ll;
    }
    // zero pad entries (u>=243 or v>=243); disjoint from all scatter writes
    if (mx == 0) {
        for (int e = tid; e < 13 * 256; e += 256) {          // u in [243,256), all v
            int u = 243 + (e >> 8), vv = e & 255;
            int idx = apk_idx(u, vv);
            ApkH[idx] = 0; ApkH[idx + 65536] = 0;
        }
        for (int e = tid; e < 243 * 13; e += 256) {          // u < 243, v in [243,256)
            int u = e / 13, vv = 243 + (e - (e / 13) * 13);
            int idx = apk_idx(u, vv);
            ApkH[idx] = 0; ApkH[idx + 65536] = 0;
        }
    }
}

// ---------------- main: 64 windows/block, MFMA 16x16x32 bf16 3-term split ----------------
// F1 two-phase scalar-walk build; F0 epilogue via LDS scalar-walk table (arena reused).
// lb(256,3): 170-VGPR budget keeps acc resident end-to-end (lb(256,4) spilled all 256 B of acc).
__global__ __launch_bounds__(256, 3) void main_ker(const float* __restrict__ x,
                                                   const uint4* __restrict__ Apk,
                                                   float* __restrict__ out) {
    __shared__ float trg[4][68];                                // c1,s1,c0,s0
    __shared__ __align__(16) unsigned char arena[33280];        // F1h|F1l, then F0[128][65] f32
    unsigned short* F1h = (unsigned short*)arena;               // 16640 B
    unsigned short* F1l = (unsigned short*)(arena + 16640);     // 16640 B
    float* F0 = (float*)arena;                                  // 128*65*4 = 33280 B
    __shared__ float red[16][16];                               // 1024 B

    int tid = threadIdx.x;
    int w0 = blockIdx.x * 64;
    int b  = blockIdx.y;
    int lane = tid & 63;
    int wave = tid >> 6;
    int wb = tid & 63;
    int wu = __builtin_amdgcn_readfirstlane(wave);   // scalar wave id -> SALU digit chains

    // stage trig rows once: sincos straight from x
    for (int p = tid; p < 68; p += 256) {
        int pos = w0 + p;
        bool ok = pos < L_SZ;
        float x1 = ok ? x[b * 8192 + 4096 + pos] : 0.f;
        float x0 = ok ? x[b * 8192 + pos] : 0.f;
        float c1v, s1v, c0v, s0v;
        __sincosf(x1, &s1v, &c1v);
        __sincosf(x0, &s0v, &c0v);
        if (!ok) { c1v = 0.f; s1v = 0.f; c0v = 0.f; s0v = 0.f; }
        trg[0][p] = c1v; trg[1][p] = s1v; trg[2][p] = c0v; trg[3][p] = s0v;
    }

    f32x4 acc[4][4];
    #pragma unroll
    for (int ut = 0; ut < 4; ++ut)
        #pragma unroll
        for (int wt = 0; wt < 4; ++wt)
            acc[ut][wt] = (f32x4){0.f, 0.f, 0.f, 0.f};

    __syncthreads();

    float c1r[5], s1r[5];
    #pragma unroll
    for (int k = 0; k < 5; ++k) { c1r[k] = trg[0][wb + k]; s1r[k] = trg[1][wb + k]; }

    const uint4* Ahi = Apk;
    const uint4* Alo = Apk + 8192;

    #pragma unroll 1
    for (int h = 0; h < 2; ++h) {
        if (h) __syncthreads();
        // ---- build F1 half h: 32 v per thread, scalar digit walk (pad rows may hold garbage:
        //      A's v>=243 columns are zero, so they never contribute) ----
        {
            int gv = h * 128 + wu * 32;                 // SGPR
            int t0 = gv / 81; int rr = gv - t0 * 81;
            int t1 = rr / 27; rr -= t1 * 27;
            int t2 = rr / 9;  rr -= t2 * 9;
            int t3 = rr / 3;  int t4 = rr - t3 * 3;
            float g0 = sel3(t0, c1r[0], s1r[0]);
            float g1 = sel3(t1, c1r[1], s1r[1]);
            float g2 = sel3(t2, c1r[2], s1r[2]);
            float g3 = sel3(t3, c1r[3], s1r[3]);
            float p0123 = g0 * g1 * g2 * g3;
            #pragma unroll
            for (int p8 = 0; p8 < 4; ++p8) {
                unsigned hw[4], lw[4];
                float prevh, prevl;
                #pragma unroll
                for (int i = 0; i < 8; ++i) {
                    float val = p0123 * sel3(t4, c1r[4], s1r[4]);
                    unsigned uxv = __float_as_uint(val);
                    float hf = __uint_as_float(uxv & 0xFFFF0000u);
                    float lf = val - hf;
                    if (i & 1) {
                        hw[i >> 1] = __byte_perm(__float_as_uint(prevh), __float_as_uint(hf), 0x7632);
                        lw[i >> 1] = __byte_perm(__float_as_uint(prevl), __float_as_uint(lf), 0x7632);
                    } else { prevh = hf; prevl = lf; }
                    if (++t4 == 3) { t4 = 0;
                        if (++t3 == 3) { t3 = 0;
                            if (++t2 == 3) { t2 = 0;
                                if (++t1 == 3) { t1 = 0; ++t0; g0 = sel3(t0, c1r[0], s1r[0]); }
                                g1 = sel3(t1, c1r[1], s1r[1]);
                            }
                            g2 = sel3(t2, c1r[2], s1r[2]);
                        }
                        g3 = sel3(t3, c1r[3], s1r[3]);
                        p0123 = g0 * g1 * g2 * g3;
                    }
                }
                int vp = wu * 4 + p8;
                *(uint4*)&F1h[(vp * 65 + wb) * 8] = make_uint4(hw[0], hw[1], hw[2], hw[3]);
                *(uint4*)&F1l[(vp * 65 + wb) * 8] = make_uint4(lw[0], lw[1], lw[2], lw[3]);
            }
        }
        __syncthreads();

        // ---- MFMA over this half's 4 K-steps ----
        #pragma unroll
        for (int kl = 0; kl < 4; ++kl) {
            int ks = h * 4 + kl;
            uint4 a_h[4], a_l[4];
            #pragma unroll
            for (int ut = 0; ut < 4; ++ut) {
                int idx = ((wave * 4 + ut) * 8 + ks) * 64 + lane;
                a_h[ut] = Ahi[idx];
                a_l[ut] = Alo[idx];
            }
            int vp = kl * 4 + (lane >> 4);
            #pragma unroll
            for (int wt = 0; wt < 4; ++wt) {
                int off = (vp * 65 + wt * 16 + (lane & 15)) * 8;
                uint4 b_h = *(const uint4*)&F1h[off];
                uint4 b_l = *(const uint4*)&F1l[off];
                bf16x8 bh = __builtin_bit_cast(bf16x8, b_h);
                bf16x8 bl = __builtin_bit_cast(bf16x8, b_l);
                #pragma unroll
                for (int ut = 0; ut < 4; ++ut) {
                    bf16x8 ah = __builtin_bit_cast(bf16x8, a_h[ut]);
                    bf16x8 al = __builtin_bit_cast(bf16x8, a_l[ut]);
                    acc[ut][wt] = __builtin_amdgcn_mfma_f32_16x16x32_bf16(ah, bh, acc[ut][wt], 0, 0, 0);
                    acc[ut][wt] = __builtin_amdgcn_mfma_f32_16x16x32_bf16(ah, bl, acc[ut][wt], 0, 0, 0);
                    acc[ut][wt] = __builtin_amdgcn_mfma_f32_16x16x32_bf16(al, bh, acc[ut][wt], 0, 0, 0);
                }
            }
        }
    }

    // ---- epilogue: z[w] = sum_u F0[u,w]*G[u,w] via LDS F0 table (arena reused),
    //      two u-half phases; F0 built by the same scalar-carry walk as F1 ----
    int c = lane & 15;
    float c0b[5], s0b[5];
    #pragma unroll
    for (int k = 0; k < 5; ++k) { c0b[k] = trg[2][wb + k]; s0b[k] = trg[3][wb + k]; }
    float zcol[4] = {0.f, 0.f, 0.f, 0.f};

    __syncthreads();                         // all F1 reads complete before arena overwrite
    #pragma unroll 1
    for (int hp = 0; hp < 2; ++hp) {
        if (hp) __syncthreads();             // hp=0 reads done before rebuild
        {
            int gu = hp * 128 + wu * 32;     // SGPR
            int t0 = gu / 81; int rr = gu - t0 * 81;
            int t1 = rr / 27; rr -= t1 * 27;
            int t2 = rr / 9;  rr -= t2 * 9;
            int t3 = rr / 3;  int t4 = rr - t3 * 3;
            float g0 = sel3(t0, c0b[0], s0b[0]);
            float g1 = sel3(t1, c0b[1], s0b[1]);
            float g2 = sel3(t2, c0b[2], s0b[2]);
            float g3 = sel3(t3, c0b[3], s0b[3]);
            float p0123 = g0 * g1 * g2 * g3;
            #pragma unroll
            for (int s = 0; s < 32; ++s) {
                float val = p0123 * sel3(t4, c0b[4], s0b[4]);   // u>=243 garbage: acc rows are 0
                F0[(wu * 32 + s) * 65 + wb] = val;
                if (++t4 == 3) { t4 = 0;
                    if (++t3 == 3) { t3 = 0;
                        if (++t2 == 3) { t2 = 0;
                            if (++t1 == 3) { t1 = 0; ++t0; g0 = sel3(t0, c0b[0], s0b[0]); }
                            g1 = sel3(t1, c0b[1], s0b[1]);
                        }
                        g2 = sel3(t2, c0b[2], s0b[2]);
                    }
                    g3 = sel3(t3, c0b[3], s0b[3]);
                    p0123 = g0 * g1 * g2 * g3;
                }
            }
        }
        __syncthreads();
        if ((wave >> 1) == hp) {             // waves whose u-band lies in this half
            int wloc = wave & 1;
            int qb = (lane >> 4) << 2;
            #pragma unroll
            for (int ut = 0; ut < 4; ++ut) {
                #pragma unroll
                for (int r = 0; r < 4; ++r) {
                    int uloc = wloc * 64 + ut * 16 + qb + r;
                    #pragma unroll
                    for (int wt = 0; wt < 4; ++wt)
                        zcol[wt] += F0[uloc * 65 + wt * 16 + c] * acc[ut][wt][r];
                }
            }
        }
    }

    // ---- reduce over u-groups: in-wave (lane>>4), then across 4 waves via LDS ----
    #pragma unroll
    for (int wt = 0; wt < 4; ++wt) {
        float v = zcol[wt];
        v += __shfl_xor(v, 16, 64);
        v += __shfl_xor(v, 32, 64);
        if ((lane >> 4) == 0) red[wave * 4 + wt][lane] = v;
    }
    __syncthreads();
    if (tid < 64) {
        int wt = tid >> 4, cc = tid & 15;
        float z = red[0 * 4 + wt][cc] + red[1 * 4 + wt][cc]
                + red[2 * 4 + wt][cc] + red[3 * 4 + wt][cc];
        int w = wt * 16 + cc;
        if (w0 + w < NWIN) out[b * NWIN + w0 + w] = z;
    }
}

extern "C" void kernel_launch(void* const* d_in, const int* in_sizes, int n_in,
                              void* d_out, int out_size, void* d_ws, size_t ws_size,
                              hipStream_t stream) {
    const float* x     = (const float*)d_in[0];
    const float* E     = (const float*)d_in[1];
    const float* theta = (const float*)d_in[2];
    float* out = (float*)d_out;
    float* ws = (float*)d_ws;

    uint4* Apk = (uint4*)(ws + APK_OFF);
    float* M   = ws + M_OFF;
    float* Mx  = ws + EXTRA_OFF;

    size_t need4 = (size_t)(EXTRA_OFF + 3 * 1048576) * 4;
    size_t need2 = (size_t)(EXTRA_OFF + 1 * 1048576) * 4;
    int S = (ws_size >= need4) ? 4 : ((ws_size >= need2) ? 2 : 1);

    mgemm_ker<<<dim3(136, 1, S), 256, 0, stream>>>(E, theta, M, Mx);
    cwht_ker<<<1024, 256, 0, stream>>>(M, Mx, S, (unsigned short*)Apk);
    main_ker<<<dim3(64, 16), 256, 0, stream>>>(x, Apk, out);
}

// Round 12
// 75.429 us; speedup vs baseline: 1.5830x; 1.1423x over previous
//
#include <hip/hip_runtime.h>
#include <math.h>

// Problem constants
#define B_SZ   16
#define L_SZ   4096
#define NWIN   4092      // (4096-5)/1+1
#define U3     243       // 3^5
#define UPAD   256

// ws layout (float offsets): Apk | M | M partials
#define APK_OFF 0                         // 16384 uint4 (hi 8192, lo 8192)
#define M_OFF   65536
#define EXTRA_OFF (M_OFF + 1048576)       // K-split partial buffers

typedef __attribute__((ext_vector_type(8))) __bf16 bf16x8;
typedef __attribute__((ext_vector_type(4))) float f32x4;

__device__ __forceinline__ float sel3(int t, float c, float s) {
    return t == 0 ? 1.0f : (t == 1 ? c : s);
}

// Apk fragment index for element C[u][v]
__device__ __forceinline__ int apk_idx(int u, int v) {
    return (((u >> 4) * 8 + (v >> 5)) * 64 + ((u & 15) | (((v >> 3) & 3) << 4))) * 8 + (v & 7);
}

// truncation split: x = hi(bf16) + lo(bf16), lo absorbs the error
__device__ __forceinline__ void bfsplit(float x, float& hf, float& lf) {
    hf = __uint_as_float(__float_as_uint(x) & 0xFFFF0000u);
    lf = x - hf;
}

// ---------------- M = E^T (G⊗I) E via MFMA 3-term bf16 split ----------------
// symmetric upper-triangle 64x64 blocks (136), z = K-split S; TILE-32 output layout:
// element (r,c) at [((r>>5)*32 + (c>>5))*1024 + (r&31)*32 + (c&31)]
__global__ __launch_bounds__(256, 4) void mgemm_ker(const float* __restrict__ E,
                                                    const float* __restrict__ theta,
                                                    float* __restrict__ M,
                                                    float* __restrict__ Mp_extra) {
    __shared__ float SA[32][72];            // fp32 stage, padded (stride 72 -> conflict-free cols)
    __shared__ float SB[32][72];
    __shared__ uint4 AfH[4 * 64], AfL[4 * 64];   // [jt][lane] fragment buffers for one k-step
    __shared__ uint4 BfH[4 * 64], BfL[4 * 64];   // [kt][lane]

    int t = blockIdx.x;
    int bj = 0;
    while (t >= 16 - bj) { t -= 16 - bj; ++bj; }
    int bk = bj + t;
    int ks = blockIdx.z;
    int tid = threadIdx.x;
    int lane = tid & 63;
    int wave = tid >> 6;

    float th = theta[0];
    float st, ct;
    __sincosf(th, &st, &ct);

    f32x4 acc[4];
    #pragma unroll
    for (int kt = 0; kt < 4; ++kt) acc[kt] = (f32x4){0.f, 0.f, 0.f, 0.f};

    int kchunk = 1024 / gridDim.z;
    int k0 = ks * kchunk;
    int lr = tid >> 3;                 // stage row 0..31
    int lcq = (tid & 7) * 8;           // stage col base (8 floats)

    for (int d0 = k0; d0 < k0 + kchunk; d0 += 32) {
        // ---- global loads (coalesced 256B/row-octet) ----
        bool hi = d0 >= 512;                         // iteration-uniform
        int dp = hi ? (d0 - 512) : (d0 + 512);
        float4 a0 = *(const float4*)&E[(d0 + lr) * 1024 + bj * 64 + lcq];
        float4 a1 = *(const float4*)&E[(d0 + lr) * 1024 + bj * 64 + lcq + 4];
        float4 q0 = *(const float4*)&E[(d0 + lr) * 1024 + bk * 64 + lcq];
        float4 q1 = *(const float4*)&E[(d0 + lr) * 1024 + bk * 64 + lcq + 4];
        float4 p0 = *(const float4*)&E[(dp + lr) * 1024 + bk * 64 + lcq];
        float4 p1 = *(const float4*)&E[(dp + lr) * 1024 + bk * 64 + lcq + 4];
        float4 y0, y1;
        if (!hi) {   // Y[d] = ct*E[d] - st*E[d+512]
            y0.x = ct * q0.x - st * p0.x; y0.y = ct * q0.y - st * p0.y;
            y0.z = ct * q0.z - st * p0.z; y0.w = ct * q0.w - st * p0.w;
            y1.x = ct * q1.x - st * p1.x; y1.y = ct * q1.y - st * p1.y;
            y1.z = ct * q1.z - st * p1.z; y1.w = ct * q1.w - st * p1.w;
        } else {     // Y[d] = -st*E[d-512] - ct*E[d]
            y0.x = -st * p0.x - ct * q0.x; y0.y = -st * p0.y - ct * q0.y;
            y0.z = -st * p0.z - ct * q0.z; y0.w = -st * p0.w - ct * q0.w;
            y1.x = -st * p1.x - ct * q1.x; y1.y = -st * p1.y - ct * q1.y;
            y1.z = -st * p1.z - ct * q1.z; y1.w = -st * p1.w - ct * q1.w;
        }
        __syncthreads();                 // prev col-reads + prev MFMA frag-reads complete
        *(float4*)&SA[lr][lcq] = a0;
        *(float4*)&SA[lr][lcq + 4] = a1;
        *(float4*)&SB[lr][lcq] = y0;
        *(float4*)&SB[lr][lcq + 4] = y1;
        __syncthreads();                 // stage visible

        // ---- column read + bf16 split + fragment build ----
        // thread: column j = lane, k-subgroup = wave (8 d's)
        {
            unsigned ahw[4], alw[4], bhw[4], blw[4];
            float pah, pal, pbh, pbl;
            #pragma unroll
            for (int i = 0; i < 8; ++i) {
                float av = SA[wave * 8 + i][lane];
                float bv = SB[wave * 8 + i][lane];
                float ah, al, bh, bl;
                bfsplit(av, ah, al);
                bfsplit(bv, bh, bl);
                if (i & 1) {
                    ahw[i >> 1] = __byte_perm(__float_as_uint(pah), __float_as_uint(ah), 0x7632);
                    alw[i >> 1] = __byte_perm(__float_as_uint(pal), __float_as_uint(al), 0x7632);
                    bhw[i >> 1] = __byte_perm(__float_as_uint(pbh), __float_as_uint(bh), 0x7632);
                    blw[i >> 1] = __byte_perm(__float_as_uint(pbl), __float_as_uint(bl), 0x7632);
                } else { pah = ah; pal = al; pbh = bh; pbl = bl; }
            }
            int slot = ((lane >> 4) << 6) + (lane & 15) + (wave << 4);   // [jt|kt][lanepos]
            AfH[slot] = make_uint4(ahw[0], ahw[1], ahw[2], ahw[3]);
            AfL[slot] = make_uint4(alw[0], alw[1], alw[2], alw[3]);
            BfH[slot] = make_uint4(bhw[0], bhw[1], bhw[2], bhw[3]);
            BfL[slot] = make_uint4(blw[0], blw[1], blw[2], blw[3]);
        }
        __syncthreads();                 // frags visible

        // ---- MFMA: wave owns jt = wave, kt = 0..3 ----
        uint4 ahu = AfH[wave * 64 + lane];
        uint4 alu = AfL[wave * 64 + lane];
        bf16x8 ah = __builtin_bit_cast(bf16x8, ahu);
        bf16x8 al = __builtin_bit_cast(bf16x8, alu);
        #pragma unroll
        for (int kt = 0; kt < 4; ++kt) {
            uint4 bhu = BfH[kt * 64 + lane];
            uint4 blu = BfL[kt * 64 + lane];
            bf16x8 bh = __builtin_bit_cast(bf16x8, bhu);
            bf16x8 bl = __builtin_bit_cast(bf16x8, blu);
            acc[kt] = __builtin_amdgcn_mfma_f32_16x16x32_bf16(ah, bh, acc[kt], 0, 0, 0);
            acc[kt] = __builtin_amdgcn_mfma_f32_16x16x32_bf16(ah, bl, acc[kt], 0, 0, 0);
            acc[kt] = __builtin_amdgcn_mfma_f32_16x16x32_bf16(al, bh, acc[kt], 0, 0, 0);
        }
    }

    // ---- epilogue: D tile (16x16) per (wave, kt); C/D map: col=lane&15, row=(lane>>4)*4+i ----
    float* dst = (ks == 0) ? M : (Mp_extra + (ks - 1) * 1048576);
    #pragma unroll
    for (int kt = 0; kt < 4; ++kt) {
        #pragma unroll
        for (int i = 0; i < 4; ++i) {
            int r = bj * 64 + wave * 16 + ((lane >> 4) << 2) + i;
            int c = bk * 64 + kt * 16 + (lane & 15);
            dst[((r >> 5) * 32 + (c >> 5)) * 1024 + (r & 31) * 32 + (c & 31)] = acc[kt][i];
        }
    }
}

// ---------------- C via WHT, scattering bf16 hi/lo into Apk; mx==0 also zeroes pads ----------------
__global__ __launch_bounds__(256) void cwht_ker(const float* __restrict__ M,
                                                const float* __restrict__ Mp_extra,
                                                int S,
                                                unsigned short* __restrict__ ApkH) {
    __shared__ float D[1024];
    int mx = blockIdx.x;
    int mxh = mx >> 5, mxl = mx & 31;
    int tid = threadIdx.x;
    float v[4];
    #pragma unroll
    for (int k = 0; k < 4; ++k) {
        int j = tid + k * 256;
        int jh = j >> 5, jl = j & 31;
        int kh = jh ^ mxh, kl = jl ^ mxl;
        int off;
        if ((jh >> 1) <= (kh >> 1)) off = ((jh * 32 + kh) * 32 + jl) * 32 + kl;
        else                        off = ((kh * 32 + jh) * 32 + kl) * 32 + jl;  // symmetric image
        float t = M[off];
        for (int s = 1; s < S; ++s) t += Mp_extra[(s - 1) * 1048576 + off];
        v[k] = t;
    }
    // stages 0..5: lane bits via shfl_xor
    #pragma unroll
    for (int s = 0; s < 6; ++s) {
        int bit = (tid >> s) & 1;
        #pragma unroll
        for (int k = 0; k < 4; ++k) {
            float p = __shfl_xor(v[k], 1 << s, 64);
            v[k] = bit ? (p - v[k]) : (v[k] + p);
        }
    }
    // stages 6,7: wave bits via one LDS round
    #pragma unroll
    for (int k = 0; k < 4; ++k) D[tid + k * 256] = v[k];
    __syncthreads();
    {
        int b6 = (tid >> 6) & 1, b7 = (tid >> 7) & 1;
        #pragma unroll
        for (int k = 0; k < 4; ++k) {
            float p64  = D[(tid ^ 64)  + k * 256];
            float p128 = D[(tid ^ 128) + k * 256];
            float p192 = D[(tid ^ 192) + k * 256];
            float ta = b6 ? (p64 - v[k])   : (v[k] + p64);
            float tb = b6 ? (p192 - p128)  : (p128 + p192);
            v[k] = b7 ? (tb - ta) : (ta + tb);
        }
    }
    // stages 8,9: k bits in-register
    {
        float a0 = v[0] + v[1], a1 = v[0] - v[1], a2 = v[2] + v[3], a3 = v[2] - v[3];
        v[0] = a0 + a2; v[1] = a1 + a3; v[2] = a0 - a2; v[3] = a1 - a3;
    }
    // scatter into Apk layout
    #pragma unroll
    for (int k = 0; k < 4; ++k) {
        int mz = tid + k * 256;
        if (mz & mx) continue;
        int u = 0, vv = 0;
        #pragma unroll
        for (int i = 0; i < 5; ++i) {
            int bit = 9 - i;
            int tt = ((mx >> bit) & 1) ? 2 : (((mz >> bit) & 1) ? 1 : 0);
            u = u * 3 + tt;
        }
        #pragma unroll
        for (int i = 5; i < 10; ++i) {
            int bit = 9 - i;
            int tt = ((mx >> bit) & 1) ? 2 : (((mz >> bit) & 1) ? 1 : 0);
            vv = vv * 3 + tt;
        }
        float val = v[k] * (1.0f / 1024.0f);
        unsigned hh = __float_as_uint(val) & 0xFFFF0000u;        // truncation split
        float lf = val - __uint_as_float(hh);
        unsigned ll = __float_as_uint(lf) >> 16;
        int idx = apk_idx(u, vv);
        ApkH[idx] = (unsigned short)(hh >> 16);
        ApkH[idx + 65536] = (unsigned short)ll;
    }
    // zero pad entries (u>=243 or v>=243); disjoint from all scatter writes
    if (mx == 0) {
        for (int e = tid; e < 13 * 256; e += 256) {          // u in [243,256), all v
            int u = 243 + (e >> 8), vv = e & 255;
            int idx = apk_idx(u, vv);
            ApkH[idx] = 0; ApkH[idx + 65536] = 0;
        }
        for (int e = tid; e < 243 * 13; e += 256) {          // u < 243, v in [243,256)
            int u = e / 13, vv = 243 + (e - (e / 13) * 13);
            int idx = apk_idx(u, vv);
            ApkH[idx] = 0; ApkH[idx + 65536] = 0;
        }
    }
}

// ---------------- main: 64 windows/block, MFMA 16x16x32 bf16 3-term split ----------------
// F1 two-phase scalar-walk build; F0 epilogue via LDS scalar-walk table (arena reused).
// lb(256,3): 170-VGPR budget keeps acc resident end-to-end.
__global__ __launch_bounds__(256, 3) void main_ker(const float* __restrict__ x,
                                                   const uint4* __restrict__ Apk,
                                                   float* __restrict__ out) {
    __shared__ float trg[4][68];                                // c1,s1,c0,s0
    __shared__ __align__(16) unsigned char arena[33280];        // F1h|F1l, then F0[128][65] f32
    unsigned short* F1h = (unsigned short*)arena;               // 16640 B
    unsigned short* F1l = (unsigned short*)(arena + 16640);     // 16640 B
    float* F0 = (float*)arena;                                  // 128*65*4 = 33280 B
    __shared__ float red[16][16];                               // 1024 B

    int tid = threadIdx.x;
    int w0 = blockIdx.x * 64;
    int b  = blockIdx.y;
    int lane = tid & 63;
    int wave = tid >> 6;
    int wb = tid & 63;
    int wu = __builtin_amdgcn_readfirstlane(wave);   // scalar wave id -> SALU digit chains

    // stage trig rows once: sincos straight from x
    for (int p = tid; p < 68; p += 256) {
        int pos = w0 + p;
        bool ok = pos < L_SZ;
        float x1 = ok ? x[b * 8192 + 4096 + pos] : 0.f;
        float x0 = ok ? x[b * 8192 + pos] : 0.f;
        float c1v, s1v, c0v, s0v;
        __sincosf(x1, &s1v, &c1v);
        __sincosf(x0, &s0v, &c0v);
        if (!ok) { c1v = 0.f; s1v = 0.f; c0v = 0.f; s0v = 0.f; }
        trg[0][p] = c1v; trg[1][p] = s1v; trg[2][p] = c0v; trg[3][p] = s0v;
    }

    f32x4 acc[4][4];
    #pragma unroll
    for (int ut = 0; ut < 4; ++ut)
        #pragma unroll
        for (int wt = 0; wt < 4; ++wt)
            acc[ut][wt] = (f32x4){0.f, 0.f, 0.f, 0.f};

    __syncthreads();

    float c1r[5], s1r[5];
    #pragma unroll
    for (int k = 0; k < 5; ++k) { c1r[k] = trg[0][wb + k]; s1r[k] = trg[1][wb + k]; }

    const uint4* Ahi = Apk;
    const uint4* Alo = Apk + 8192;

    #pragma unroll 1
    for (int h = 0; h < 2; ++h) {
        if (h) __syncthreads();
        // ---- build F1 half h: 32 v per thread, scalar digit walk (pad rows garbage-safe:
        //      A's v>=243 columns are zero) ----
        {
            int gv = h * 128 + wu * 32;                 // SGPR
            int t0 = gv / 81; int rr = gv - t0 * 81;
            int t1 = rr / 27; rr -= t1 * 27;
            int t2 = rr / 9;  rr -= t2 * 9;
            int t3 = rr / 3;  int t4 = rr - t3 * 3;
            float g0 = sel3(t0, c1r[0], s1r[0]);
            float g1 = sel3(t1, c1r[1], s1r[1]);
            float g2 = sel3(t2, c1r[2], s1r[2]);
            float g3 = sel3(t3, c1r[3], s1r[3]);
            float p0123 = g0 * g1 * g2 * g3;
            #pragma unroll
            for (int p8 = 0; p8 < 4; ++p8) {
                unsigned hw[4], lw[4];
                float prevh, prevl;
                #pragma unroll
                for (int i = 0; i < 8; ++i) {
                    float val = p0123 * sel3(t4, c1r[4], s1r[4]);
                    float hf, lf;
                    bfsplit(val, hf, lf);
                    if (i & 1) {
                        hw[i >> 1] = __byte_perm(__float_as_uint(prevh), __float_as_uint(hf), 0x7632);
                        lw[i >> 1] = __byte_perm(__float_as_uint(prevl), __float_as_uint(lf), 0x7632);
                    } else { prevh = hf; prevl = lf; }
                    if (++t4 == 3) { t4 = 0;
                        if (++t3 == 3) { t3 = 0;
                            if (++t2 == 3) { t2 = 0;
                                if (++t1 == 3) { t1 = 0; ++t0; g0 = sel3(t0, c1r[0], s1r[0]); }
                                g1 = sel3(t1, c1r[1], s1r[1]);
                            }
                            g2 = sel3(t2, c1r[2], s1r[2]);
                        }
                        g3 = sel3(t3, c1r[3], s1r[3]);
                        p0123 = g0 * g1 * g2 * g3;
                    }
                }
                int vp = wu * 4 + p8;
                *(uint4*)&F1h[(vp * 65 + wb) * 8] = make_uint4(hw[0], hw[1], hw[2], hw[3]);
                *(uint4*)&F1l[(vp * 65 + wb) * 8] = make_uint4(lw[0], lw[1], lw[2], lw[3]);
            }
        }
        __syncthreads();

        // ---- MFMA over this half's 4 K-steps ----
        #pragma unroll
        for (int kl = 0; kl < 4; ++kl) {
            int ks = h * 4 + kl;
            uint4 a_h[4], a_l[4];
            #pragma unroll
            for (int ut = 0; ut < 4; ++ut) {
                int idx = ((wave * 4 + ut) * 8 + ks) * 64 + lane;
                a_h[ut] = Ahi[idx];
                a_l[ut] = Alo[idx];
            }
            int vp = kl * 4 + (lane >> 4);
            #pragma unroll
            for (int wt = 0; wt < 4; ++wt) {
                int off = (vp * 65 + wt * 16 + (lane & 15)) * 8;
                uint4 b_h = *(const uint4*)&F1h[off];
                uint4 b_l = *(const uint4*)&F1l[off];
                bf16x8 bh = __builtin_bit_cast(bf16x8, b_h);
                bf16x8 bl = __builtin_bit_cast(bf16x8, b_l);
                #pragma unroll
                for (int ut = 0; ut < 4; ++ut) {
                    bf16x8 ah = __builtin_bit_cast(bf16x8, a_h[ut]);
                    bf16x8 al = __builtin_bit_cast(bf16x8, a_l[ut]);
                    acc[ut][wt] = __builtin_amdgcn_mfma_f32_16x16x32_bf16(ah, bh, acc[ut][wt], 0, 0, 0);
                    acc[ut][wt] = __builtin_amdgcn_mfma_f32_16x16x32_bf16(ah, bl, acc[ut][wt], 0, 0, 0);
                    acc[ut][wt] = __builtin_amdgcn_mfma_f32_16x16x32_bf16(al, bh, acc[ut][wt], 0, 0, 0);
                }
            }
        }
    }

    // ---- epilogue: z[w] = sum_u F0[u,w]*G[u,w] via LDS F0 table (arena reused) ----
    int c = lane & 15;
    float c0b[5], s0b[5];
    #pragma unroll
    for (int k = 0; k < 5; ++k) { c0b[k] = trg[2][wb + k]; s0b[k] = trg[3][wb + k]; }
    float zcol[4] = {0.f, 0.f, 0.f, 0.f};

    __syncthreads();                         // all F1 reads complete before arena overwrite
    #pragma unroll 1
    for (int hp = 0; hp < 2; ++hp) {
        if (hp) __syncthreads();             // hp=0 reads done before rebuild
        {
            int gu = hp * 128 + wu * 32;     // SGPR
            int t0 = gu / 81; int rr = gu - t0 * 81;
            int t1 = rr / 27; rr -= t1 * 27;
            int t2 = rr / 9;  rr -= t2 * 9;
            int t3 = rr / 3;  int t4 = rr - t3 * 3;
            float g0 = sel3(t0, c0b[0], s0b[0]);
            float g1 = sel3(t1, c0b[1], s0b[1]);
            float g2 = sel3(t2, c0b[2], s0b[2]);
            float g3 = sel3(t3, c0b[3], s0b[3]);
            float p0123 = g0 * g1 * g2 * g3;
            #pragma unroll
            for (int s = 0; s < 32; ++s) {
                float val = p0123 * sel3(t4, c0b[4], s0b[4]);   // u>=243 garbage: acc rows are 0
                F0[(wu * 32 + s) * 65 + wb] = val;
                if (++t4 == 3) { t4 = 0;
                    if (++t3 == 3) { t3 = 0;
                        if (++t2 == 3) { t2 = 0;
                            if (++t1 == 3) { t1 = 0; ++t0; g0 = sel3(t0, c0b[0], s0b[0]); }
                            g1 = sel3(t1, c0b[1], s0b[1]);
                        }
                        g2 = sel3(t2, c0b[2], s0b[2]);
                    }
                    g3 = sel3(t3, c0b[3], s0b[3]);
                    p0123 = g0 * g1 * g2 * g3;
                }
            }
        }
        __syncthreads();
        if ((wave >> 1) == hp) {             // waves whose u-band lies in this half
            int wloc = wave & 1;
            int qb = (lane >> 4) << 2;
            #pragma unroll
            for (int ut = 0; ut < 4; ++ut) {
                #pragma unroll
                for (int r = 0; r < 4; ++r) {
                    int uloc = wloc * 64 + ut * 16 + qb + r;
                    #pragma unroll
                    for (int wt = 0; wt < 4; ++wt)
                        zcol[wt] += F0[uloc * 65 + wt * 16 + c] * acc[ut][wt][r];
                }
            }
        }
    }

    // ---- reduce over u-groups: in-wave (lane>>4), then across 4 waves via LDS ----
    #pragma unroll
    for (int wt = 0; wt < 4; ++wt) {
        float v = zcol[wt];
        v += __shfl_xor(v, 16, 64);
        v += __shfl_xor(v, 32, 64);
        if ((lane >> 4) == 0) red[wave * 4 + wt][lane] = v;
    }
    __syncthreads();
    if (tid < 64) {
        int wt = tid >> 4, cc = tid & 15;
        float z = red[0 * 4 + wt][cc] + red[1 * 4 + wt][cc]
                + red[2 * 4 + wt][cc] + red[3 * 4 + wt][cc];
        int w = wt * 16 + cc;
        if (w0 + w < NWIN) out[b * NWIN + w0 + w] = z;
    }
}

extern "C" void kernel_launch(void* const* d_in, const int* in_sizes, int n_in,
                              void* d_out, int out_size, void* d_ws, size_t ws_size,
                              hipStream_t stream) {
    const float* x     = (const float*)d_in[0];
    const float* E     = (const float*)d_in[1];
    const float* theta = (const float*)d_in[2];
    float* out = (float*)d_out;
    float* ws = (float*)d_ws;

    uint4* Apk = (uint4*)(ws + APK_OFF);
    float* M   = ws + M_OFF;
    float* Mx  = ws + EXTRA_OFF;

    size_t need2 = (size_t)(EXTRA_OFF + 1 * 1048576) * 4;
    int S = (ws_size >= need2) ? 2 : 1;

    mgemm_ker<<<dim3(136, 1, S), 256, 0, stream>>>(E, theta, M, Mx);
    cwht_ker<<<1024, 256, 0, stream>>>(M, Mx, S, (unsigned short*)Apk);
    main_ker<<<dim3(64, 16), 256, 0, stream>>>(x, Apk, out);
}